// Round 7
// baseline (367.050 us; speedup 1.0000x reference)
//
#include <hip/hip_runtime.h>
#include <hip/hip_bf16.h>

typedef __attribute__((ext_vector_type(4))) float f32x4;
typedef __attribute__((ext_vector_type(16))) float f32x16;
typedef __attribute__((ext_vector_type(8))) __bf16 bf16x8;
typedef __attribute__((ext_vector_type(4))) __bf16 bf16x4;
typedef __attribute__((ext_vector_type(4))) unsigned int u32x4;

static constexpr int E    = 1024;
static constexpr int TOK  = 8192;   // 8 * 1024 tokens
static constexpr int HID  = 4096;

#define DEVINL __device__ __forceinline__

// async global->LDS, 16B per lane. LDS dest must be lane-linear (wave base + lane*16).
DEVINL void gload16(const void* g, void* l) {
  __builtin_amdgcn_global_load_lds((__attribute__((address_space(1))) void*)g,
                                   (__attribute__((address_space(3))) void*)l, 16, 0, 0);
}

#define ABAR()  asm volatile("s_barrier" ::: "memory")
#define AVM(n)  asm volatile("s_waitcnt vmcnt(" #n ")" ::: "memory")
#define CVTPK(dst, lo, hi) asm("v_cvt_pk_bf16_f32 %0, %1, %2" : "=v"(dst) : "v"(lo), "v"(hi))
#define PLSWAP(a, b) asm("v_permlane32_swap_b32 %0, %1" : "+v"(a), "+v"(b))

template <int N> DEVINL void avm() {
  if constexpr (N == 0)      asm volatile("s_waitcnt vmcnt(0)" ::: "memory");
  else if constexpr (N == 2) asm volatile("s_waitcnt vmcnt(2)" ::: "memory");
  else if constexpr (N == 8) asm volatile("s_waitcnt vmcnt(8)" ::: "memory");
  else if constexpr (N == 9) asm volatile("s_waitcnt vmcnt(9)" ::: "memory");
  else                       asm volatile("s_waitcnt vmcnt(0)" ::: "memory");
}

// ---------------------------------------------------------------------------
// Weight convert + transpose: W[K][N] f32 -> Wt[N][K] bf16 (32x32 LDS tiles)
// ---------------------------------------------------------------------------
__global__ __launch_bounds__(256) void wconv_kernel(const float* __restrict__ W,
                                                    __bf16* __restrict__ Wt,
                                                    int K, int N) {
  __shared__ float tile[32][33];
  const int t  = threadIdx.x;
  const long k0 = (long)blockIdx.y * 32;
  const long n0 = (long)blockIdx.x * 32;
  const int r  = t >> 3;
  const int c4 = (t & 7) * 4;
  float4 v = *(const float4*)&W[(k0 + r) * N + n0 + c4];
  tile[r][c4 + 0] = v.x; tile[r][c4 + 1] = v.y;
  tile[r][c4 + 2] = v.z; tile[r][c4 + 3] = v.w;
  __syncthreads();
  bf16x4 o;
#pragma unroll
  for (int i = 0; i < 4; ++i) o[i] = (__bf16)tile[c4 + i][r];
  *(bf16x4*)&Wt[(n0 + r) * K + k0 + c4] = o;
}

// ---------------------------------------------------------------------------
// LayerNorm (fp32 in) -> bf16 out. One block per row of 1024.
// ---------------------------------------------------------------------------
__global__ __launch_bounds__(256) void ln_kernel(const float* __restrict__ X,
                                                 const float* __restrict__ g,
                                                 const float* __restrict__ be,
                                                 __bf16* __restrict__ O) {
  const int t = threadIdx.x;
  const long row = blockIdx.x;
  float4 v = *(const float4*)&X[row * E + t * 4];
  float s  = v.x + v.y + v.z + v.w;
  float ss = v.x * v.x + v.y * v.y + v.z * v.z + v.w * v.w;
#pragma unroll
  for (int off = 32; off; off >>= 1) {
    s  += __shfl_down(s, off);
    ss += __shfl_down(ss, off);
  }
  __shared__ float red[8];
  const int w = t >> 6;
  if ((t & 63) == 0) { red[w] = s; red[4 + w] = ss; }
  __syncthreads();
  s  = red[0] + red[1] + red[2] + red[3];
  ss = red[4] + red[5] + red[6] + red[7];
  const float mean = s * (1.0f / E);
  const float var  = ss * (1.0f / E) - mean * mean;
  const float rstd = rsqrtf(var + 1e-5f);
  float4 gv = *(const float4*)&g[t * 4];
  float4 bv = *(const float4*)&be[t * 4];
  bf16x4 o;
  o[0] = (__bf16)((v.x - mean) * rstd * gv.x + bv.x);
  o[1] = (__bf16)((v.y - mean) * rstd * gv.y + bv.y);
  o[2] = (__bf16)((v.z - mean) * rstd * gv.z + bv.z);
  o[3] = (__bf16)((v.w - mean) * rstd * gv.w + bv.w);
  *(bf16x4*)&O[row * E + t * 4] = o;
}

// ---------------------------------------------------------------------------
// Deep-pipelined BK=32 GEMM: C[M][N] = op(A[M][K] @ Bt[N][K]^T + bias)(+resid)
// BM_ in {256,128}, BN=256. 512 threads = 8 waves (2 wr x 4 wc).
// Per-wave output (BM_/2)x64: row = m*32+wr*16, col = n*64+wc*16.
// DEPTH LDS buffers of (BM_*64 + 16384) bytes; stage tile t+DEPTH-1 during t.
// One vmcnt(W)+s_barrier per K-tile, W=(DEPTH-2)*TL; waited loads are DEPTH-1
// tiles old (>=1000cy) -> covers HBM/L3 latency. Never vmcnt(0) in loop.
// Swizzle (64B rows, 4x16B pieces): piece = kp ^ ((row>>1)&3), both sides.
// Per 16-lane quarter: 2 rows per 16B slot -> 2-way = free.
// ---------------------------------------------------------------------------
template <int BM_, int DEPTH, bool RELU, bool RESID, bool OUTBF, int NB>
__global__ __launch_bounds__(512, 2) void gemmk_kernel(const __bf16* __restrict__ A,
                                                       const __bf16* __restrict__ Bt,
                                                       const float* __restrict__ bias0,
                                                       const float* __restrict__ bias1,
                                                       const float* __restrict__ bias2,
                                                       const float* resid,
                                                       void* Cout,
                                                       int M, int N, int K) {
  extern __shared__ char lds[];
  constexpr int MF    = BM_ / 32;            // m-frags per wave (8 or 4)
  constexpr int ABYT  = BM_ * 64;            // A buffer bytes (BM_*32*2)
  constexpr int TILEB = ABYT + 16384;        // per-buffer bytes
  constexpr int AL    = BM_ / 128;           // A loads/thread/tile (2 or 1)
  constexpr int TL    = AL + 2;              // total loads/thread/tile
  constexpr int W     = (DEPTH - 2) * TL;    // vmcnt wait value

  const int tid  = threadIdx.x;
  const int lane = tid & 63;
  const int l15  = lane & 15;
  const int kp   = lane >> 4;                // k-piece 0..3
  const int wid  = tid >> 6;
  const int wr   = wid >> 2;   // 0..1
  const int wc   = wid & 3;    // 0..3

  // XCD-aware swizzle (all grids have nwg % 8 == 0)
  const int nwg  = gridDim.x * gridDim.y;
  const int flat = blockIdx.x + gridDim.x * blockIdx.y;
  const int swz  = (flat & 7) * (nwg >> 3) + (flat >> 3);
  const int bx   = swz % gridDim.x;
  const int by   = swz / gridDim.x;
  const long brow = (long)by * BM_;
  const long bcol = (long)bx * 256;

  const __bf16* Ab = A  + brow * K;
  const __bf16* Bb = Bt + bcol * K;
  const int NT = K >> 5;

  // stage tile (BK=32) into buffer base; pre-swizzled global source
  auto stageA = [&](int k0, char* dst) {
#pragma unroll
    for (int i = 0; i < AL; ++i) {
      const int c = i * 512 + tid;
      const int r = c >> 2;
      const int p = (c & 3) ^ ((r >> 1) & 3);
      gload16(Ab + (long)r * K + k0 + p * 8, dst + c * 16);
    }
  };
  auto stageB = [&](int k0, char* dst) {
#pragma unroll
    for (int i = 0; i < 2; ++i) {
      const int c = i * 512 + tid;
      const int r = c >> 2;
      const int p = (c & 3) ^ ((r >> 1) & 3);
      gload16(Bb + (long)r * K + k0 + p * 8, dst + c * 16);
    }
  };

  f32x4 acc[MF][4];
  const f32x4 z4 = {0.f, 0.f, 0.f, 0.f};
#pragma unroll
  for (int m = 0; m < MF; ++m)
#pragma unroll
    for (int n = 0; n < 4; ++n) acc[m][n] = z4;

  // ---- prologue: stage tiles 0..DEPTH-2 ----
#pragma unroll
  for (int pt = 0; pt < DEPTH - 1; ++pt) {
    stageA(pt * 32, lds + pt * TILEB);
    stageB(pt * 32, lds + pt * TILEB + ABYT);
  }

  bf16x8 af[MF > 4 ? 4 : MF], bfr[4];

  for (int t = 0; t < NT; ++t) {
    const int cb = t % DEPTH;
    const int sb = (t + DEPTH - 1) % DEPTH;
    const char* Ac = lds + cb * TILEB;
    const char* Bc = Ac + ABYT;
    char* An = lds + sb * TILEB;
    const int kt = (t + DEPTH - 1 < NT) ? ((t + DEPTH - 1) << 5) : 0;

    avm<W>();    // drains exactly tile t's loads (issued DEPTH-1 tiles ago)
    ABAR();      // publish: every wave's tile-t DMA confirmed

    if constexpr (BM_ == 256) {
      // ---- phase 1: A m0-3 + all B; stage A(t+3); 16 MFMA ----
#pragma unroll
      for (int m = 0; m < 4; ++m) {
        const int row = m * 32 + wr * 16 + l15;
        af[m] = *(const bf16x8*)(Ac + row * 64 + (kp ^ ((row >> 1) & 3)) * 16);
      }
#pragma unroll
      for (int n = 0; n < 4; ++n) {
        const int col = n * 64 + wc * 16 + l15;
        bfr[n] = *(const bf16x8*)(Bc + col * 64 + (kp ^ ((col >> 1) & 3)) * 16);
      }
      stageA(kt, An);
      __builtin_amdgcn_s_setprio(1);
#pragma unroll
      for (int m = 0; m < 4; ++m)
#pragma unroll
        for (int n = 0; n < 4; ++n)
          acc[m][n] = __builtin_amdgcn_mfma_f32_16x16x32_bf16(af[m], bfr[n], acc[m][n], 0, 0, 0);
      __builtin_amdgcn_s_setprio(0);
      // ---- phase 2: A m4-7; stage B(t+3); 16 MFMA ----
#pragma unroll
      for (int m = 0; m < 4; ++m) {
        const int row = (m + 4) * 32 + wr * 16 + l15;
        af[m] = *(const bf16x8*)(Ac + row * 64 + (kp ^ ((row >> 1) & 3)) * 16);
      }
      stageB(kt, An + ABYT);
      __builtin_amdgcn_s_setprio(1);
#pragma unroll
      for (int m = 0; m < 4; ++m)
#pragma unroll
        for (int n = 0; n < 4; ++n)
          acc[m + 4][n] = __builtin_amdgcn_mfma_f32_16x16x32_bf16(af[m], bfr[n], acc[m + 4][n], 0, 0, 0);
      __builtin_amdgcn_s_setprio(0);
    } else {
      // ---- single phase: A m0-3 + B; stage A+B(t+4); 16 MFMA ----
#pragma unroll
      for (int m = 0; m < 4; ++m) {
        const int row = m * 32 + wr * 16 + l15;
        af[m] = *(const bf16x8*)(Ac + row * 64 + (kp ^ ((row >> 1) & 3)) * 16);
      }
#pragma unroll
      for (int n = 0; n < 4; ++n) {
        const int col = n * 64 + wc * 16 + l15;
        bfr[n] = *(const bf16x8*)(Bc + col * 64 + (kp ^ ((col >> 1) & 3)) * 16);
      }
      stageA(kt, An);
      stageB(kt, An + ABYT);
      __builtin_amdgcn_s_setprio(1);
#pragma unroll
      for (int m = 0; m < 4; ++m)
#pragma unroll
        for (int n = 0; n < 4; ++n)
          acc[m][n] = __builtin_amdgcn_mfma_f32_16x16x32_bf16(af[m], bfr[n], acc[m][n], 0, 0, 0);
      __builtin_amdgcn_s_setprio(0);
    }
  }
  avm<0>();  // drain tail dummy stages

  // ---- epilogue. D layout: col=lane&15, row=(lane>>4)*4+j within frag ----
#pragma unroll
  for (int m = 0; m < MF; ++m) {
#pragma unroll
    for (int n = 0; n < 4; ++n) {
      const long col = bcol + n * 64 + wc * 16 + l15;
      float bb;
      if (NB == 3) {
        const float* bp = (col < 1024) ? bias0 : ((col < 2048) ? bias1 : bias2);
        bb = bp[col & 1023];
      } else {
        bb = bias0[col];
      }
#pragma unroll
      for (int j = 0; j < 4; ++j) {
        const long row = brow + m * 32 + wr * 16 + (lane >> 4) * 4 + j;
        float val = acc[m][n][j] + bb;
        if (RELU) val = fmaxf(val, 0.f);
        const long idx = row * N + col;
        if (RESID) val += resid[idx];
        if (OUTBF) ((__bf16*)Cout)[idx] = (__bf16)val;
        else       ((float*)Cout)[idx]  = val;
      }
    }
  }
}

// ---------------------------------------------------------------------------
// Flash attention, swapped-operand 32x32 structure (m214-style). Unchanged.
// ---------------------------------------------------------------------------
__global__ __launch_bounds__(256, 3) void attn_kernel(const __bf16* __restrict__ QKV,
                                                      __bf16* __restrict__ Og) {
  __shared__ __align__(16) __bf16 Qs[128 * 64];    // 16KB [qrow][d]
  __shared__ __align__(16) __bf16 Ks[2][64 * 64];  // 2x8KB [key][d]
  __shared__ __align__(16) __bf16 Vt[2][64 * 64];  // 2x8KB [d][key]

  const int QSTR = 3072;
  const int t    = threadIdx.x;
  const int lane = t & 63;
  const int w    = t >> 6;       // wave 0..3
  const int l31  = lane & 31;
  const int h    = lane >> 5;    // half 0/1
  const int b    = blockIdx.y >> 4;
  const int hh   = blockIdx.y & 15;
  const long row0 = (long)b * 1024 + (long)blockIdx.x * 128;
  const long kvrow0 = (long)b * 1024;
  const int colQ = hh * 64;
  const int colK = colQ + 1024;
  const int colV = colQ + 2048;

  // ---- prologue: stage Q (once), K[0], V[0] ----
#pragma unroll
  for (int j = 0; j < 4; ++j) {
    const int c = j * 256 + t;
    const int r = c >> 3;
    const int p = (c & 7) ^ (r & 7);
    gload16(QKV + (row0 + r) * QSTR + colQ + p * 8, (char*)Qs + c * 16);
  }
#pragma unroll
  for (int j = 0; j < 2; ++j) {
    const int c = j * 256 + t;
    const int r = c >> 3;
    const int p = (c & 7) ^ (r & 7);
    gload16(QKV + (kvrow0 + r) * QSTR + colK + p * 8, (char*)Ks[0] + c * 16);
  }
  bf16x8 vv[2];
#pragma unroll
  for (int j = 0; j < 2; ++j) {
    const int c = j * 256 + t;
    const int key = c >> 3, dc = c & 7;
    vv[j] = *(const bf16x8*)(QKV + (kvrow0 + key) * QSTR + colV + dc * 8);
  }
  AVM(0);
#pragma unroll
  for (int j = 0; j < 2; ++j) {
    const int c = j * 256 + t;
    const int key = c >> 3, dc = c & 7;
#pragma unroll
    for (int e = 0; e < 8; ++e) {
      const int d = dc * 8 + e;
      *(__bf16*)((char*)Vt[0] + d * 128 + (((key >> 3) ^ dc) * 16) + (key & 7) * 2) = vv[j][e];
    }
  }
  __syncthreads();

  // hoist Q fragments (B-operand: col=q=l31, k-chunk = kk*16 + h*8)
  bf16x8 bq[4];
  {
    const int qrow = w * 32 + l31;
#pragma unroll
    for (int kk = 0; kk < 4; ++kk) {
      const int p = (kk * 2 + h) ^ (qrow & 7);
      bq[kk] = *(const bf16x8*)((const char*)Qs + qrow * 128 + p * 16);
    }
  }

  f32x16 ctx0, ctx1;
#pragma unroll
  for (int r = 0; r < 16; ++r) { ctx0[r] = 0.f; ctx1[r] = 0.f; }
  float m = -INFINITY, l = 0.f;

  for (int kb = 0; kb < 16; ++kb) {
    const int cur = kb & 1, nxt = cur ^ 1;
    const int kb1 = (kb + 1 < 16) ? kb + 1 : kb;
    const long kr1 = kvrow0 + kb1 * 64;

    // prefetch next tile: V reg-loads first, then K global->LDS
#pragma unroll
    for (int j = 0; j < 2; ++j) {
      const int c = j * 256 + t;
      const int key = c >> 3, dc = c & 7;
      vv[j] = *(const bf16x8*)(QKV + (kr1 + key) * QSTR + colV + dc * 8);
    }
#pragma unroll
    for (int j = 0; j < 2; ++j) {
      const int c = j * 256 + t;
      const int r = c >> 3;
      const int p = (c & 7) ^ (r & 7);
      gload16(QKV + (kr1 + r) * QSTR + colK + p * 8, (char*)Ks[nxt] + c * 16);
    }

    // ---- QK^T swapped: A=K rows(keys), B=Q cols(q) ----
    f32x16 s0, s1;
#pragma unroll
    for (int r = 0; r < 16; ++r) { s0[r] = 0.f; s1[r] = 0.f; }
    __builtin_amdgcn_s_setprio(1);
#pragma unroll
    for (int kk = 0; kk < 4; ++kk) {
      const int pce = kk * 2 + h;
      const int p0i = pce ^ (l31 & 7);
      bf16x8 ak0 = *(const bf16x8*)((const char*)Ks[cur] + l31 * 128 + p0i * 16);
      bf16x8 ak1 = *(const bf16x8*)((const char*)Ks[cur] + (32 + l31) * 128 + p0i * 16);
      s0 = __builtin_amdgcn_mfma_f32_32x32x16_bf16(ak0, bq[kk], s0, 0, 0, 0);
      s1 = __builtin_amdgcn_mfma_f32_32x32x16_bf16(ak1, bq[kk], s1, 0, 0, 0);
    }
    __builtin_amdgcn_s_setprio(0);

    // ---- in-register online softmax (raw units; scale 1/8 folded into exp) ----
    float mx = s0[0];
#pragma unroll
    for (int r = 1; r < 16; ++r) mx = fmaxf(mx, s0[r]);
#pragma unroll
    for (int r = 0; r < 16; ++r) mx = fmaxf(mx, s1[r]);
    mx = fmaxf(mx, __shfl_xor(mx, 32));

    if (!__all(mx - m <= 64.f)) {   // defer-max THR = 8 (x8 raw)
      const float mn = fmaxf(m, mx);
      const float corr = __expf((m - mn) * 0.125f);
      l *= corr;
#pragma unroll
      for (int r = 0; r < 16; ++r) { ctx0[r] *= corr; ctx1[r] *= corr; }
      m = mn;
    }
    f32x16 p0, p1;
    float rs = 0.f;
#pragma unroll
    for (int r = 0; r < 16; ++r) { p0[r] = __expf((s0[r] - m) * 0.125f); rs += p0[r]; }
#pragma unroll
    for (int r = 0; r < 16; ++r) { p1[r] = __expf((s1[r] - m) * 0.125f); rs += p1[r]; }
    rs += __shfl_xor(rs, 32);
    l += rs;

    // ---- write V[t+1] transpose into Vt[nxt] ----
    AVM(2);
#pragma unroll
    for (int j = 0; j < 2; ++j) {
      const int c = j * 256 + t;
      const int key = c >> 3, dc = c & 7;
#pragma unroll
      for (int e = 0; e < 8; ++e) {
        const int d = dc * 8 + e;
        *(__bf16*)((char*)Vt[nxt] + d * 128 + (((key >> 3) ^ dc) * 16) + (key & 7) * 2) = vv[j][e];
      }
    }

    // ---- build PV B-operand frags: pa[ks][e] = P[k=ks*16+h*8+e][q] ----
    bf16x8 paf[4];
#pragma unroll
    for (int ks = 0; ks < 4; ++ks) {
      const int base = (ks & 1) * 8;
      unsigned a0, a1, b0, b1;
      if (ks < 2) {
        CVTPK(a0, p0[base + 0], p0[base + 1]);
        CVTPK(b0, p0[base + 4], p0[base + 5]);
        CVTPK(a1, p0[base + 2], p0[base + 3]);
        CVTPK(b1, p0[base + 6], p0[base + 7]);
      } else {
        CVTPK(a0, p1[base + 0], p1[base + 1]);
        CVTPK(b0, p1[base + 4], p1[base + 5]);
        CVTPK(a1, p1[base + 2], p1[base + 3]);
        CVTPK(b1, p1[base + 6], p1[base + 7]);
      }
      PLSWAP(a0, b0);   // a0 -> word0, b0 -> word2
      PLSWAP(a1, b1);   // a1 -> word1, b1 -> word3
      u32x4 wv4; wv4[0] = a0; wv4[1] = a1; wv4[2] = b0; wv4[3] = b1;
      paf[ks] = __builtin_bit_cast(bf16x8, wv4);
    }

    // ---- PV swapped: ctx(O^T) += mfma(A=Vt rows(d), B=P cols(q)) ----
    __builtin_amdgcn_s_setprio(1);
#pragma unroll
    for (int ks = 0; ks < 4; ++ks) {
      const int pce = ks * 2 + h;
      bf16x8 av0 = *(const bf16x8*)((const char*)Vt[cur] + l31 * 128 + ((pce ^ (l31 >> 3)) * 16));
      bf16x8 av1 = *(const bf16x8*)((const char*)Vt[cur] + (32 + l31) * 128 + ((pce ^ (4 + (l31 >> 3))) * 16));
      ctx0 = __builtin_amdgcn_mfma_f32_32x32x16_bf16(av0, paf[ks], ctx0, 0, 0, 0);
      ctx1 = __builtin_amdgcn_mfma_f32_32x32x16_bf16(av1, paf[ks], ctx1, 0, 0, 0);
    }
    __builtin_amdgcn_s_setprio(0);

    __syncthreads();   // drains vmcnt (K[t+1] landed) + publishes Vt[nxt]
  }

  // ---- epilogue: O[q][d] = ctx^T / l ; d = (r&3)+8*(r>>2)+4h+32f ----
  const float inv = 1.0f / l;
  const long orow = row0 + w * 32 + l31;
#pragma unroll
  for (int f = 0; f < 2; ++f)
#pragma unroll
    for (int tq = 0; tq < 4; ++tq) {
      bf16x4 o;
#pragma unroll
      for (int e = 0; e < 4; ++e) {
        const float v = (f ? ctx1[tq * 4 + e] : ctx0[tq * 4 + e]) * inv;
        o[e] = (__bf16)v;
      }
      const int col = colQ + f * 32 + tq * 8 + h * 4;
      *(bf16x4*)&Og[orow * E + col] = o;
    }
}

// ---------------------------------------------------------------------------
extern "C" void kernel_launch(void* const* d_in, const int* in_sizes, int n_in,
                              void* d_out, int out_size, void* d_ws, size_t ws_size,
                              hipStream_t stream) {
  const float* x     = (const float*)d_in[0];
  const float* ln1g  = (const float*)d_in[1];
  const float* ln1b  = (const float*)d_in[2];
  const float* ln2g  = (const float*)d_in[3];
  const float* ln2b  = (const float*)d_in[4];
  const float* wq    = (const float*)d_in[5];
  const float* bq    = (const float*)d_in[6];
  const float* wk    = (const float*)d_in[7];
  const float* bk    = (const float*)d_in[8];
  const float* wv    = (const float*)d_in[9];
  const float* bv    = (const float*)d_in[10];
  const float* wo    = (const float*)d_in[11];
  const float* bo    = (const float*)d_in[12];
  const float* w1    = (const float*)d_in[13];
  const float* b1    = (const float*)d_in[14];
  const float* w2    = (const float*)d_in[15];
  const float* b2    = (const float*)d_in[16];
  float* out = (float*)d_out;

  char* ws = (char*)d_ws;
  const size_t MB = 1024 * 1024;
  __bf16* Wqkv = (__bf16*)(ws + 0 * MB);    // [3072][1024] bf16, 6MB (q|k|v rows)
  __bf16* Wot  = (__bf16*)(ws + 6 * MB);    // [1024][1024] 2MB
  __bf16* W1t  = (__bf16*)(ws + 8 * MB);    // [4096][1024] 8MB
  __bf16* W2t  = (__bf16*)(ws + 16 * MB);   // [1024][4096] 8MB
  __bf16* h    = (__bf16*)(ws + 24 * MB);   // [8192][1024] 16MB
  __bf16* qkv  = (__bf16*)(ws + 40 * MB);   // [8192][3072] 48MB
  __bf16* ctx  = (__bf16*)(ws + 88 * MB);   // [8192][1024] 16MB (total 104MB)
  __bf16* ff1  = (__bf16*)(ws + 40 * MB);   // [8192][4096] 64MB, aliases qkv (dead)

  const dim3 blk(256);
  const dim3 blk512(512);
  const size_t GLDS256 = 4 * (256 * 64 + 16384);   // 128 KB, DEPTH=4
  const size_t GLDS128 = 5 * (128 * 64 + 16384);   // 120 KB, DEPTH=5

  // weights -> bf16 transposed [N][K]; q/k/v stacked into Wqkv
  wconv_kernel<<<dim3(E / 32, E / 32), blk, 0, stream>>>(wq, Wqkv, E, E);
  wconv_kernel<<<dim3(E / 32, E / 32), blk, 0, stream>>>(wk, Wqkv + 1024 * 1024, E, E);
  wconv_kernel<<<dim3(E / 32, E / 32), blk, 0, stream>>>(wv, Wqkv + 2048 * 1024, E, E);
  wconv_kernel<<<dim3(E / 32, E / 32), blk, 0, stream>>>(wo, Wot, E, E);
  wconv_kernel<<<dim3(HID / 32, E / 32), blk, 0, stream>>>(w1, W1t, E, HID);
  wconv_kernel<<<dim3(E / 32, HID / 32), blk, 0, stream>>>(w2, W2t, HID, E);

  // LN1
  ln_kernel<<<TOK, blk, 0, stream>>>(x, ln1g, ln1b, h);

  // fused QKV projection: [8192][3072]   grid 12x32 = 384 blocks
  gemmk_kernel<256, 4, false, false, true, 3><<<dim3(3072 / 256, TOK / 256), blk512, GLDS256, stream>>>(
      h, Wqkv, bq, bk, bv, nullptr, qkv, TOK, 3072, E);

  // attention: 8 q-blocks of 128 rows x 128 (b,h)
  attn_kernel<<<dim3(8, 128), blk, 0, stream>>>(qkv, ctx);

  // O projection + residual(x) -> d_out (fp32)   grid 4x64 = 256 blocks
  gemmk_kernel<128, 5, false, true, false, 1><<<dim3(E / 256, TOK / 128), blk512, GLDS128, stream>>>(
      ctx, Wot, bo, nullptr, nullptr, x, out, TOK, E, E);

  // LN2 on d_out
  ln_kernel<<<TOK, blk, 0, stream>>>(out, ln2g, ln2b, h);

  // FF1 with ReLU -> ff1 (bf16)   grid 16x32 = 512 blocks
  gemmk_kernel<256, 4, true, false, true, 1><<<dim3(HID / 256, TOK / 256), blk512, GLDS256, stream>>>(
      h, W1t, b1, nullptr, nullptr, nullptr, ff1, TOK, HID, E);

  // FF2 + residual(d_out) -> d_out (in-place, element-wise safe)   grid 4x64 = 256
  gemmk_kernel<128, 5, false, true, false, 1><<<dim3(E / 256, TOK / 128), blk512, GLDS128, stream>>>(
      ff1, W2t, b2, nullptr, nullptr, out, out, TOK, E, HID);
}

// Round 8
// 364.792 us; speedup vs baseline: 1.0062x; 1.0062x over previous
//
#include <hip/hip_runtime.h>
#include <hip/hip_bf16.h>

typedef __attribute__((ext_vector_type(4))) float f32x4;
typedef __attribute__((ext_vector_type(16))) float f32x16;
typedef __attribute__((ext_vector_type(8))) __bf16 bf16x8;
typedef __attribute__((ext_vector_type(4))) __bf16 bf16x4;
typedef __attribute__((ext_vector_type(4))) unsigned int u32x4;

static constexpr int E    = 1024;
static constexpr int TOK  = 8192;   // 8 * 1024 tokens
static constexpr int HID  = 4096;

#define DEVINL __device__ __forceinline__

// async global->LDS, 16B per lane. LDS dest must be lane-linear (wave base + lane*16).
DEVINL void gload16(const void* g, void* l) {
  __builtin_amdgcn_global_load_lds((__attribute__((address_space(1))) void*)g,
                                   (__attribute__((address_space(3))) void*)l, 16, 0, 0);
}

#define ABAR()  asm volatile("s_barrier" ::: "memory")
#define AVM(n)  asm volatile("s_waitcnt vmcnt(" #n ")" ::: "memory")
#define ALGKM0() do { asm volatile("s_waitcnt lgkmcnt(0)" ::: "memory"); \
                      __builtin_amdgcn_sched_barrier(0); } while (0)
#define CVTPK(dst, lo, hi) asm("v_cvt_pk_bf16_f32 %0, %1, %2" : "=v"(dst) : "v"(lo), "v"(hi))
#define PLSWAP(a, b) asm("v_permlane32_swap_b32 %0, %1" : "+v"(a), "+v"(b))

template <int N> DEVINL void avm() {
  if constexpr (N == 0)      asm volatile("s_waitcnt vmcnt(0)" ::: "memory");
  else if constexpr (N == 2) asm volatile("s_waitcnt vmcnt(2)" ::: "memory");
  else if constexpr (N == 8) asm volatile("s_waitcnt vmcnt(8)" ::: "memory");
  else if constexpr (N == 9) asm volatile("s_waitcnt vmcnt(9)" ::: "memory");
  else                       asm volatile("s_waitcnt vmcnt(0)" ::: "memory");
}

// ---------------------------------------------------------------------------
// Weight convert + transpose: W[K][N] f32 -> Wt[N][K] bf16 (32x32 LDS tiles)
// ---------------------------------------------------------------------------
__global__ __launch_bounds__(256) void wconv_kernel(const float* __restrict__ W,
                                                    __bf16* __restrict__ Wt,
                                                    int K, int N) {
  __shared__ float tile[32][33];
  const int t  = threadIdx.x;
  const long k0 = (long)blockIdx.y * 32;
  const long n0 = (long)blockIdx.x * 32;
  const int r  = t >> 3;
  const int c4 = (t & 7) * 4;
  float4 v = *(const float4*)&W[(k0 + r) * N + n0 + c4];
  tile[r][c4 + 0] = v.x; tile[r][c4 + 1] = v.y;
  tile[r][c4 + 2] = v.z; tile[r][c4 + 3] = v.w;
  __syncthreads();
  bf16x4 o;
#pragma unroll
  for (int i = 0; i < 4; ++i) o[i] = (__bf16)tile[c4 + i][r];
  *(bf16x4*)&Wt[(n0 + r) * K + k0 + c4] = o;
}

// ---------------------------------------------------------------------------
// LayerNorm (fp32 in) -> bf16 out. One block per row of 1024.
// ---------------------------------------------------------------------------
__global__ __launch_bounds__(256) void ln_kernel(const float* __restrict__ X,
                                                 const float* __restrict__ g,
                                                 const float* __restrict__ be,
                                                 __bf16* __restrict__ O) {
  const int t = threadIdx.x;
  const long row = blockIdx.x;
  float4 v = *(const float4*)&X[row * E + t * 4];
  float s  = v.x + v.y + v.z + v.w;
  float ss = v.x * v.x + v.y * v.y + v.z * v.z + v.w * v.w;
#pragma unroll
  for (int off = 32; off; off >>= 1) {
    s  += __shfl_down(s, off);
    ss += __shfl_down(ss, off);
  }
  __shared__ float red[8];
  const int w = t >> 6;
  if ((t & 63) == 0) { red[w] = s; red[4 + w] = ss; }
  __syncthreads();
  s  = red[0] + red[1] + red[2] + red[3];
  ss = red[4] + red[5] + red[6] + red[7];
  const float mean = s * (1.0f / E);
  const float var  = ss * (1.0f / E) - mean * mean;
  const float rstd = rsqrtf(var + 1e-5f);
  float4 gv = *(const float4*)&g[t * 4];
  float4 bv = *(const float4*)&be[t * 4];
  bf16x4 o;
  o[0] = (__bf16)((v.x - mean) * rstd * gv.x + bv.x);
  o[1] = (__bf16)((v.y - mean) * rstd * gv.y + bv.y);
  o[2] = (__bf16)((v.z - mean) * rstd * gv.z + bv.z);
  o[3] = (__bf16)((v.w - mean) * rstd * gv.w + bv.w);
  *(bf16x4*)&O[row * E + t * 4] = o;
}

// ---------------------------------------------------------------------------
// Reduce for split-K FF2: out = out(resid, in-place) + bias + tmp0 + tmp1.
// One float4 per thread over [8192][1024] fp32.
// ---------------------------------------------------------------------------
__global__ __launch_bounds__(256) void reduce2_kernel(float* __restrict__ out,
                                                      const __bf16* __restrict__ t0,
                                                      const __bf16* __restrict__ t1,
                                                      const float* __restrict__ b2) {
  const int i = blockIdx.x * 256 + threadIdx.x;   // 2M groups of float4
  float4 o = ((const float4*)out)[i];
  bf16x4 a = ((const bf16x4*)t0)[i];
  bf16x4 b = ((const bf16x4*)t1)[i];
  float4 bb = ((const float4*)b2)[i & 255];
  o.x += bb.x + (float)a[0] + (float)b[0];
  o.y += bb.y + (float)a[1] + (float)b[1];
  o.z += bb.z + (float)a[2] + (float)b[2];
  o.w += bb.w + (float)a[3] + (float)b[3];
  ((float4*)out)[i] = o;
}

// ---------------------------------------------------------------------------
// Deep-pipelined BK=32 GEMM with phase-locked two-barrier MFMA clusters.
// C[M][N] = op(A[M][K] @ Bt[N][K]^T + bias)(+resid). KLD = row stride of A/Bt
// (K = extent, may be < KLD for split-K; blockIdx.z selects K-slice and dst).
// BM_ in {256,128}, BN=256. 512 threads = 8 waves (2 wr x 4 wc).
// DEPTH ring of (BM_*64 + 16384)B one-K-tile buffers; stage tile t+DEPTH-1
// during tile t; one vmcnt(W)+barrier per tile, W=(DEPTH-2)*TL (never 0).
// Phase interior (m201 rhythm): {ds_read issue; stage; s_barrier; lgkmcnt(0)
// +sched_barrier; setprio(1); 16 MFMA; setprio(0); s_barrier}.
// Swizzle (64B rows, 4x16B pieces): piece = kp ^ ((row>>1)&3), both sides.
// ---------------------------------------------------------------------------
template <int BM_, int DEPTH, bool RELU, bool RESID, bool OUTBF, int NB>
__global__ __launch_bounds__(512, 2) void gemmk_kernel(const __bf16* __restrict__ A,
                                                       const __bf16* __restrict__ Bt,
                                                       const float* __restrict__ bias0,
                                                       const float* __restrict__ bias1,
                                                       const float* __restrict__ bias2,
                                                       const float* resid,
                                                       void* Cout, void* Cout2,
                                                       int M, int N, int K, int KLD) {
  extern __shared__ char lds[];
  constexpr int MF    = BM_ / 32;            // m-frags per wave (8 or 4)
  constexpr int ABYT  = BM_ * 64;            // A buffer bytes (BM_*32*2)
  constexpr int TILEB = ABYT + 16384;        // per-buffer bytes
  constexpr int AL    = BM_ / 128;           // A loads/thread/tile (2 or 1)
  constexpr int TL    = AL + 2;              // total loads/thread/tile
  constexpr int W     = (DEPTH - 2) * TL;    // vmcnt wait value

  const int tid  = threadIdx.x;
  const int lane = tid & 63;
  const int l15  = lane & 15;
  const int kp   = lane >> 4;                // k-piece 0..3
  const int wid  = tid >> 6;
  const int wr   = wid >> 2;   // 0..1
  const int wc   = wid & 3;    // 0..3

  // XCD-aware swizzle over the full 3D grid (nwg % 8 == 0 everywhere)
  const int gx   = gridDim.x, gy = gridDim.y;
  const int nwg  = gx * gy * gridDim.z;
  const int flat = blockIdx.x + gx * (blockIdx.y + gy * blockIdx.z);
  const int swz  = (flat & 7) * (nwg >> 3) + (flat >> 3);
  const int bx   = swz % gx;
  const int by   = (swz / gx) % gy;
  const int bz   = swz / (gx * gy);
  const long brow = (long)by * BM_;
  const long bcol = (long)bx * 256;
  const long koff = (long)bz * K;

  const __bf16* Ab = A  + brow * KLD + koff;
  const __bf16* Bb = Bt + bcol * KLD + koff;
  void* Cdst = bz ? Cout2 : Cout;
  const int NT = K >> 5;

  auto stageA = [&](int k0, char* dst) {
#pragma unroll
    for (int i = 0; i < AL; ++i) {
      const int c = i * 512 + tid;
      const int r = c >> 2;
      const int p = (c & 3) ^ ((r >> 1) & 3);
      gload16(Ab + (long)r * KLD + k0 + p * 8, dst + c * 16);
    }
  };
  auto stageB = [&](int k0, char* dst) {
#pragma unroll
    for (int i = 0; i < 2; ++i) {
      const int c = i * 512 + tid;
      const int r = c >> 2;
      const int p = (c & 3) ^ ((r >> 1) & 3);
      gload16(Bb + (long)r * KLD + k0 + p * 8, dst + c * 16);
    }
  };

  f32x4 acc[MF][4];
  const f32x4 z4 = {0.f, 0.f, 0.f, 0.f};
#pragma unroll
  for (int m = 0; m < MF; ++m)
#pragma unroll
    for (int n = 0; n < 4; ++n) acc[m][n] = z4;

  // ---- prologue: stage tiles 0..DEPTH-2 ----
#pragma unroll
  for (int pt = 0; pt < DEPTH - 1; ++pt) {
    stageA(pt * 32, lds + pt * TILEB);
    stageB(pt * 32, lds + pt * TILEB + ABYT);
  }

  bf16x8 af[4], bfr[4];

  for (int t = 0; t < NT; ++t) {
    const int cb = t % DEPTH;
    const int sb = (t + DEPTH - 1) % DEPTH;
    const char* Ac = lds + cb * TILEB;
    const char* Bc = Ac + ABYT;
    char* An = lds + sb * TILEB;
    const int kt = (t + DEPTH - 1 < NT) ? ((t + DEPTH - 1) << 5) : 0;

    avm<W>();    // drains exactly tile t's loads (issued DEPTH-1 tiles ago)
    ABAR();      // publish: every wave's tile-t DMA confirmed

    if constexpr (BM_ == 256) {
      // ---- phase 1: issue A m0-3 + all B reads; stage A(t+3) ----
#pragma unroll
      for (int m = 0; m < 4; ++m) {
        const int row = m * 32 + wr * 16 + l15;
        af[m] = *(const bf16x8*)(Ac + row * 64 + (kp ^ ((row >> 1) & 3)) * 16);
      }
#pragma unroll
      for (int n = 0; n < 4; ++n) {
        const int col = n * 64 + wc * 16 + l15;
        bfr[n] = *(const bf16x8*)(Bc + col * 64 + (kp ^ ((col >> 1) & 3)) * 16);
      }
      stageA(kt, An);
      ABAR();
      ALGKM0();
      __builtin_amdgcn_s_setprio(1);
#pragma unroll
      for (int m = 0; m < 4; ++m)
#pragma unroll
        for (int n = 0; n < 4; ++n)
          acc[m][n] = __builtin_amdgcn_mfma_f32_16x16x32_bf16(af[m], bfr[n], acc[m][n], 0, 0, 0);
      __builtin_amdgcn_s_setprio(0);
      ABAR();
      // ---- phase 2: issue A m4-7 reads; stage B(t+3) ----
#pragma unroll
      for (int m = 0; m < 4; ++m) {
        const int row = (m + 4) * 32 + wr * 16 + l15;
        af[m] = *(const bf16x8*)(Ac + row * 64 + (kp ^ ((row >> 1) & 3)) * 16);
      }
      stageB(kt, An + ABYT);
      ABAR();
      ALGKM0();
      __builtin_amdgcn_s_setprio(1);
#pragma unroll
      for (int m = 0; m < 4; ++m)
#pragma unroll
        for (int n = 0; n < 4; ++n)
          acc[m + 4][n] = __builtin_amdgcn_mfma_f32_16x16x32_bf16(af[m], bfr[n], acc[m + 4][n], 0, 0, 0);
      __builtin_amdgcn_s_setprio(0);
    } else {
      // ---- single phase: issue A m0-3 + B reads; stage A+B(t+4) ----
#pragma unroll
      for (int m = 0; m < 4; ++m) {
        const int row = m * 32 + wr * 16 + l15;
        af[m] = *(const bf16x8*)(Ac + row * 64 + (kp ^ ((row >> 1) & 3)) * 16);
      }
#pragma unroll
      for (int n = 0; n < 4; ++n) {
        const int col = n * 64 + wc * 16 + l15;
        bfr[n] = *(const bf16x8*)(Bc + col * 64 + (kp ^ ((col >> 1) & 3)) * 16);
      }
      stageA(kt, An);
      stageB(kt, An + ABYT);
      ABAR();
      ALGKM0();
      __builtin_amdgcn_s_setprio(1);
#pragma unroll
      for (int m = 0; m < 4; ++m)
#pragma unroll
        for (int n = 0; n < 4; ++n)
          acc[m][n] = __builtin_amdgcn_mfma_f32_16x16x32_bf16(af[m], bfr[n], acc[m][n], 0, 0, 0);
      __builtin_amdgcn_s_setprio(0);
    }
  }
  avm<0>();  // drain tail dummy stages

  // ---- epilogue. D layout: col=lane&15, row=(lane>>4)*4+j within frag ----
#pragma unroll
  for (int m = 0; m < MF; ++m) {
#pragma unroll
    for (int n = 0; n < 4; ++n) {
      const long col = bcol + n * 64 + wc * 16 + l15;
      float bb;
      if (NB == 3) {
        const float* bp = (col < 1024) ? bias0 : ((col < 2048) ? bias1 : bias2);
        bb = bp[col & 1023];
      } else if (NB == 1) {
        bb = bias0[col];
      } else {
        bb = 0.f;
      }
#pragma unroll
      for (int j = 0; j < 4; ++j) {
        const long row = brow + m * 32 + wr * 16 + (lane >> 4) * 4 + j;
        float val = acc[m][n][j] + bb;
        if (RELU) val = fmaxf(val, 0.f);
        const long idx = row * N + col;
        if (RESID) val += resid[idx];
        if (OUTBF) ((__bf16*)Cdst)[idx] = (__bf16)val;
        else       ((float*)Cdst)[idx]  = val;
      }
    }
  }
}

// ---------------------------------------------------------------------------
// Flash attention, swapped-operand 32x32 structure (m214-style). Unchanged.
// ---------------------------------------------------------------------------
__global__ __launch_bounds__(256, 3) void attn_kernel(const __bf16* __restrict__ QKV,
                                                      __bf16* __restrict__ Og) {
  __shared__ __align__(16) __bf16 Qs[128 * 64];    // 16KB [qrow][d]
  __shared__ __align__(16) __bf16 Ks[2][64 * 64];  // 2x8KB [key][d]
  __shared__ __align__(16) __bf16 Vt[2][64 * 64];  // 2x8KB [d][key]

  const int QSTR = 3072;
  const int t    = threadIdx.x;
  const int lane = t & 63;
  const int w    = t >> 6;       // wave 0..3
  const int l31  = lane & 31;
  const int h    = lane >> 5;    // half 0/1
  const int b    = blockIdx.y >> 4;
  const int hh   = blockIdx.y & 15;
  const long row0 = (long)b * 1024 + (long)blockIdx.x * 128;
  const long kvrow0 = (long)b * 1024;
  const int colQ = hh * 64;
  const int colK = colQ + 1024;
  const int colV = colQ + 2048;

  // ---- prologue: stage Q (once), K[0], V[0] ----
#pragma unroll
  for (int j = 0; j < 4; ++j) {
    const int c = j * 256 + t;
    const int r = c >> 3;
    const int p = (c & 7) ^ (r & 7);
    gload16(QKV + (row0 + r) * QSTR + colQ + p * 8, (char*)Qs + c * 16);
  }
#pragma unroll
  for (int j = 0; j < 2; ++j) {
    const int c = j * 256 + t;
    const int r = c >> 3;
    const int p = (c & 7) ^ (r & 7);
    gload16(QKV + (kvrow0 + r) * QSTR + colK + p * 8, (char*)Ks[0] + c * 16);
  }
  bf16x8 vv[2];
#pragma unroll
  for (int j = 0; j < 2; ++j) {
    const int c = j * 256 + t;
    const int key = c >> 3, dc = c & 7;
    vv[j] = *(const bf16x8*)(QKV + (kvrow0 + key) * QSTR + colV + dc * 8);
  }
  AVM(0);
#pragma unroll
  for (int j = 0; j < 2; ++j) {
    const int c = j * 256 + t;
    const int key = c >> 3, dc = c & 7;
#pragma unroll
    for (int e = 0; e < 8; ++e) {
      const int d = dc * 8 + e;
      *(__bf16*)((char*)Vt[0] + d * 128 + (((key >> 3) ^ dc) * 16) + (key & 7) * 2) = vv[j][e];
    }
  }
  __syncthreads();

  // hoist Q fragments (B-operand: col=q=l31, k-chunk = kk*16 + h*8)
  bf16x8 bq[4];
  {
    const int qrow = w * 32 + l31;
#pragma unroll
    for (int kk = 0; kk < 4; ++kk) {
      const int p = (kk * 2 + h) ^ (qrow & 7);
      bq[kk] = *(const bf16x8*)((const char*)Qs + qrow * 128 + p * 16);
    }
  }

  f32x16 ctx0, ctx1;
#pragma unroll
  for (int r = 0; r < 16; ++r) { ctx0[r] = 0.f; ctx1[r] = 0.f; }
  float m = -INFINITY, l = 0.f;

  for (int kb = 0; kb < 16; ++kb) {
    const int cur = kb & 1, nxt = cur ^ 1;
    const int kb1 = (kb + 1 < 16) ? kb + 1 : kb;
    const long kr1 = kvrow0 + kb1 * 64;

    // prefetch next tile: V reg-loads first, then K global->LDS
#pragma unroll
    for (int j = 0; j < 2; ++j) {
      const int c = j * 256 + t;
      const int key = c >> 3, dc = c & 7;
      vv[j] = *(const bf16x8*)(QKV + (kr1 + key) * QSTR + colV + dc * 8);
    }
#pragma unroll
    for (int j = 0; j < 2; ++j) {
      const int c = j * 256 + t;
      const int r = c >> 3;
      const int p = (c & 7) ^ (r & 7);
      gload16(QKV + (kr1 + r) * QSTR + colK + p * 8, (char*)Ks[nxt] + c * 16);
    }

    // ---- QK^T swapped: A=K rows(keys), B=Q cols(q) ----
    f32x16 s0, s1;
#pragma unroll
    for (int r = 0; r < 16; ++r) { s0[r] = 0.f; s1[r] = 0.f; }
    __builtin_amdgcn_s_setprio(1);
#pragma unroll
    for (int kk = 0; kk < 4; ++kk) {
      const int pce = kk * 2 + h;
      const int p0i = pce ^ (l31 & 7);
      bf16x8 ak0 = *(const bf16x8*)((const char*)Ks[cur] + l31 * 128 + p0i * 16);
      bf16x8 ak1 = *(const bf16x8*)((const char*)Ks[cur] + (32 + l31) * 128 + p0i * 16);
      s0 = __builtin_amdgcn_mfma_f32_32x32x16_bf16(ak0, bq[kk], s0, 0, 0, 0);
      s1 = __builtin_amdgcn_mfma_f32_32x32x16_bf16(ak1, bq[kk], s1, 0, 0, 0);
    }
    __builtin_amdgcn_s_setprio(0);

    // ---- in-register online softmax (raw units; scale 1/8 folded into exp) ----
    float mx = s0[0];
#pragma unroll
    for (int r = 1; r < 16; ++r) mx = fmaxf(mx, s0[r]);
#pragma unroll
    for (int r = 0; r < 16; ++r) mx = fmaxf(mx, s1[r]);
    mx = fmaxf(mx, __shfl_xor(mx, 32));

    if (!__all(mx - m <= 64.f)) {   // defer-max THR = 8 (x8 raw)
      const float mn = fmaxf(m, mx);
      const float corr = __expf((m - mn) * 0.125f);
      l *= corr;
#pragma unroll
      for (int r = 0; r < 16; ++r) { ctx0[r] *= corr; ctx1[r] *= corr; }
      m = mn;
    }
    f32x16 p0, p1;
    float rs = 0.f;
#pragma unroll
    for (int r = 0; r < 16; ++r) { p0[r] = __expf((s0[r] - m) * 0.125f); rs += p0[r]; }
#pragma unroll
    for (int r = 0; r < 16; ++r) { p1[r] = __expf((s1[r] - m) * 0.125f); rs += p1[r]; }
    rs += __shfl_xor(rs, 32);
    l += rs;

    // ---- write V[t+1] transpose into Vt[nxt] ----
    AVM(2);
#pragma unroll
    for (int j = 0; j < 2; ++j) {
      const int c = j * 256 + t;
      const int key = c >> 3, dc = c & 7;
#pragma unroll
      for (int e = 0; e < 8; ++e) {
        const int d = dc * 8 + e;
        *(__bf16*)((char*)Vt[nxt] + d * 128 + (((key >> 3) ^ dc) * 16) + (key & 7) * 2) = vv[j][e];
      }
    }

    // ---- build PV B-operand frags: pa[ks][e] = P[k=ks*16+h*8+e][q] ----
    bf16x8 paf[4];
#pragma unroll
    for (int ks = 0; ks < 4; ++ks) {
      const int base = (ks & 1) * 8;
      unsigned a0, a1, b0, b1;
      if (ks < 2) {
        CVTPK(a0, p0[base + 0], p0[base + 1]);
        CVTPK(b0, p0[base + 4], p0[base + 5]);
        CVTPK(a1, p0[base + 2], p0[base + 3]);
        CVTPK(b1, p0[base + 6], p0[base + 7]);
      } else {
        CVTPK(a0, p1[base + 0], p1[base + 1]);
        CVTPK(b0, p1[base + 4], p1[base + 5]);
        CVTPK(a1, p1[base + 2], p1[base + 3]);
        CVTPK(b1, p1[base + 6], p1[base + 7]);
      }
      PLSWAP(a0, b0);   // a0 -> word0, b0 -> word2
      PLSWAP(a1, b1);   // a1 -> word1, b1 -> word3
      u32x4 wv4; wv4[0] = a0; wv4[1] = a1; wv4[2] = b0; wv4[3] = b1;
      paf[ks] = __builtin_bit_cast(bf16x8, wv4);
    }

    // ---- PV swapped: ctx(O^T) += mfma(A=Vt rows(d), B=P cols(q)) ----
    __builtin_amdgcn_s_setprio(1);
#pragma unroll
    for (int ks = 0; ks < 4; ++ks) {
      const int pce = ks * 2 + h;
      bf16x8 av0 = *(const bf16x8*)((const char*)Vt[cur] + l31 * 128 + ((pce ^ (l31 >> 3)) * 16));
      bf16x8 av1 = *(const bf16x8*)((const char*)Vt[cur] + (32 + l31) * 128 + ((pce ^ (4 + (l31 >> 3))) * 16));
      ctx0 = __builtin_amdgcn_mfma_f32_32x32x16_bf16(av0, paf[ks], ctx0, 0, 0, 0);
      ctx1 = __builtin_amdgcn_mfma_f32_32x32x16_bf16(av1, paf[ks], ctx1, 0, 0, 0);
    }
    __builtin_amdgcn_s_setprio(0);

    __syncthreads();   // drains vmcnt (K[t+1] landed) + publishes Vt[nxt]
  }

  // ---- epilogue: O[q][d] = ctx^T / l ; d = (r&3)+8*(r>>2)+4h+32f ----
  const float inv = 1.0f / l;
  const long orow = row0 + w * 32 + l31;
#pragma unroll
  for (int f = 0; f < 2; ++f)
#pragma unroll
    for (int tq = 0; tq < 4; ++tq) {
      bf16x4 o;
#pragma unroll
      for (int e = 0; e < 4; ++e) {
        const float v = (f ? ctx1[tq * 4 + e] : ctx0[tq * 4 + e]) * inv;
        o[e] = (__bf16)v;
      }
      const int col = colQ + f * 32 + tq * 8 + h * 4;
      *(bf16x4*)&Og[orow * E + col] = o;
    }
}

// ---------------------------------------------------------------------------
extern "C" void kernel_launch(void* const* d_in, const int* in_sizes, int n_in,
                              void* d_out, int out_size, void* d_ws, size_t ws_size,
                              hipStream_t stream) {
  const float* x     = (const float*)d_in[0];
  const float* ln1g  = (const float*)d_in[1];
  const float* ln1b  = (const float*)d_in[2];
  const float* ln2g  = (const float*)d_in[3];
  const float* ln2b  = (const float*)d_in[4];
  const float* wq    = (const float*)d_in[5];
  const float* bq    = (const float*)d_in[6];
  const float* wk    = (const float*)d_in[7];
  const float* bk    = (const float*)d_in[8];
  const float* wv    = (const float*)d_in[9];
  const float* bv    = (const float*)d_in[10];
  const float* wo    = (const float*)d_in[11];
  const float* bo    = (const float*)d_in[12];
  const float* w1    = (const float*)d_in[13];
  const float* b1    = (const float*)d_in[14];
  const float* w2    = (const float*)d_in[15];
  const float* b2    = (const float*)d_in[16];
  float* out = (float*)d_out;

  char* ws = (char*)d_ws;
  const size_t MB = 1024 * 1024;
  __bf16* Wqkv = (__bf16*)(ws + 0 * MB);    // [3072][1024] bf16, 6MB (q|k|v rows)
  __bf16* Wot  = (__bf16*)(ws + 6 * MB);    // [1024][1024] 2MB
  __bf16* W1t  = (__bf16*)(ws + 8 * MB);    // [4096][1024] 8MB
  __bf16* W2t  = (__bf16*)(ws + 16 * MB);   // [1024][4096] 8MB
  __bf16* h    = (__bf16*)(ws + 24 * MB);   // [8192][1024] 16MB
  __bf16* qkv  = (__bf16*)(ws + 40 * MB);   // [8192][3072] 48MB
  __bf16* ctx  = (__bf16*)(ws + 88 * MB);   // [8192][1024] 16MB (total 104MB)
  __bf16* ff1  = (__bf16*)(ws + 40 * MB);   // [8192][4096] 64MB, aliases qkv (dead)
  __bf16* tmp0 = (__bf16*)(ws + 0 * MB);    // FF2 split-K partial 0 (weights dead)
  __bf16* tmp1 = (__bf16*)(ws + 24 * MB);   // FF2 split-K partial 1 (h dead)

  const dim3 blk(256);
  const dim3 blk512(512);
  const size_t GLDS256 = 4 * (256 * 64 + 16384);   // 128 KB, DEPTH=4
  const size_t GLDS128 = 5 * (128 * 64 + 16384);   // 120 KB, DEPTH=5

  // weights -> bf16 transposed [N][K]; q/k/v stacked into Wqkv
  wconv_kernel<<<dim3(E / 32, E / 32), blk, 0, stream>>>(wq, Wqkv, E, E);
  wconv_kernel<<<dim3(E / 32, E / 32), blk, 0, stream>>>(wk, Wqkv + 1024 * 1024, E, E);
  wconv_kernel<<<dim3(E / 32, E / 32), blk, 0, stream>>>(wv, Wqkv + 2048 * 1024, E, E);
  wconv_kernel<<<dim3(E / 32, E / 32), blk, 0, stream>>>(wo, Wot, E, E);
  wconv_kernel<<<dim3(HID / 32, E / 32), blk, 0, stream>>>(w1, W1t, E, HID);
  wconv_kernel<<<dim3(E / 32, HID / 32), blk, 0, stream>>>(w2, W2t, HID, E);

  // LN1
  ln_kernel<<<TOK, blk, 0, stream>>>(x, ln1g, ln1b, h);

  // fused QKV projection: [8192][3072]   grid 12x32 = 384 blocks
  gemmk_kernel<256, 4, false, false, true, 3><<<dim3(3072 / 256, TOK / 256), blk512, GLDS256, stream>>>(
      h, Wqkv, bq, bk, bv, nullptr, qkv, nullptr, TOK, 3072, E, E);

  // attention: 8 q-blocks of 128 rows x 128 (b,h)
  attn_kernel<<<dim3(8, 128), blk, 0, stream>>>(qkv, ctx);

  // O projection + residual(x) -> d_out (fp32)   grid 4x64 = 256 blocks
  gemmk_kernel<128, 5, false, true, false, 1><<<dim3(E / 256, TOK / 128), blk512, GLDS128, stream>>>(
      ctx, Wot, bo, nullptr, nullptr, x, out, nullptr, TOK, E, E, E);

  // LN2 on d_out
  ln_kernel<<<TOK, blk, 0, stream>>>(out, ln2g, ln2b, h);

  // FF1 with ReLU -> ff1 (bf16)   grid 16x32 = 512 blocks
  gemmk_kernel<256, 4, true, false, true, 1><<<dim3(HID / 256, TOK / 256), blk512, GLDS256, stream>>>(
      h, W1t, b1, nullptr, nullptr, nullptr, ff1, nullptr, TOK, HID, E, E);

  // FF2 split-K=2: partials (bf16, no bias) -> tmp0/tmp1   grid 4x32x2 = 256 blocks
  gemmk_kernel<256, 4, false, false, true, 0><<<dim3(E / 256, TOK / 256, 2), blk512, GLDS256, stream>>>(
      ff1, W2t, nullptr, nullptr, nullptr, nullptr, tmp0, tmp1, TOK, E, HID / 2, HID);

  // reduce: out = out(resid) + b2 + tmp0 + tmp1   (8192 blocks x 256 thr x float4)
  reduce2_kernel<<<TOK * E / 1024, blk, 0, stream>>>(out, tmp0, tmp1, b2);
}

// Round 9
// 358.527 us; speedup vs baseline: 1.0238x; 1.0175x over previous
//
#include <hip/hip_runtime.h>
#include <hip/hip_bf16.h>

typedef __attribute__((ext_vector_type(4))) float f32x4;
typedef __attribute__((ext_vector_type(16))) float f32x16;
typedef __attribute__((ext_vector_type(8))) __bf16 bf16x8;
typedef __attribute__((ext_vector_type(4))) __bf16 bf16x4;
typedef __attribute__((ext_vector_type(4))) unsigned int u32x4;

static constexpr int E    = 1024;
static constexpr int TOK  = 8192;   // 8 * 1024 tokens
static constexpr int HID  = 4096;

#define DEVINL __device__ __forceinline__

// async global->LDS, 16B per lane. LDS dest must be lane-linear (wave base + lane*16).
DEVINL void gload16(const void* g, void* l) {
  __builtin_amdgcn_global_load_lds((__attribute__((address_space(1))) void*)g,
                                   (__attribute__((address_space(3))) void*)l, 16, 0, 0);
}

#define ABAR()  asm volatile("s_barrier" ::: "memory")
#define AVM(n)  asm volatile("s_waitcnt vmcnt(" #n ")" ::: "memory")
#define ALGKM0() do { asm volatile("s_waitcnt lgkmcnt(0)" ::: "memory"); \
                      __builtin_amdgcn_sched_barrier(0); } while (0)
#define CVTPK(dst, lo, hi) asm("v_cvt_pk_bf16_f32 %0, %1, %2" : "=v"(dst) : "v"(lo), "v"(hi))
#define PLSWAP(a, b) asm("v_permlane32_swap_b32 %0, %1" : "+v"(a), "+v"(b))

template <int N> DEVINL void avm() {
  if constexpr (N == 0)      asm volatile("s_waitcnt vmcnt(0)" ::: "memory");
  else if constexpr (N == 2) asm volatile("s_waitcnt vmcnt(2)" ::: "memory");
  else if constexpr (N == 6) asm volatile("s_waitcnt vmcnt(6)" ::: "memory");
  else if constexpr (N == 8) asm volatile("s_waitcnt vmcnt(8)" ::: "memory");
  else if constexpr (N == 9) asm volatile("s_waitcnt vmcnt(9)" ::: "memory");
  else                       asm volatile("s_waitcnt vmcnt(0)" ::: "memory");
}

// ---------------------------------------------------------------------------
// Weight convert + transpose: W[K][N] f32 -> Wt[N][K] bf16 (32x32 LDS tiles)
// ---------------------------------------------------------------------------
__global__ __launch_bounds__(256) void wconv_kernel(const float* __restrict__ W,
                                                    __bf16* __restrict__ Wt,
                                                    int K, int N) {
  __shared__ float tile[32][33];
  const int t  = threadIdx.x;
  const long k0 = (long)blockIdx.y * 32;
  const long n0 = (long)blockIdx.x * 32;
  const int r  = t >> 3;
  const int c4 = (t & 7) * 4;
  float4 v = *(const float4*)&W[(k0 + r) * N + n0 + c4];
  tile[r][c4 + 0] = v.x; tile[r][c4 + 1] = v.y;
  tile[r][c4 + 2] = v.z; tile[r][c4 + 3] = v.w;
  __syncthreads();
  bf16x4 o;
#pragma unroll
  for (int i = 0; i < 4; ++i) o[i] = (__bf16)tile[c4 + i][r];
  *(bf16x4*)&Wt[(n0 + r) * K + k0 + c4] = o;
}

// ---------------------------------------------------------------------------
// LayerNorm (fp32 in) -> bf16 out. One block per row of 1024.
// ---------------------------------------------------------------------------
__global__ __launch_bounds__(256) void ln_kernel(const float* __restrict__ X,
                                                 const float* __restrict__ g,
                                                 const float* __restrict__ be,
                                                 __bf16* __restrict__ O) {
  const int t = threadIdx.x;
  const long row = blockIdx.x;
  float4 v = *(const float4*)&X[row * E + t * 4];
  float s  = v.x + v.y + v.z + v.w;
  float ss = v.x * v.x + v.y * v.y + v.z * v.z + v.w * v.w;
#pragma unroll
  for (int off = 32; off; off >>= 1) {
    s  += __shfl_down(s, off);
    ss += __shfl_down(ss, off);
  }
  __shared__ float red[8];
  const int w = t >> 6;
  if ((t & 63) == 0) { red[w] = s; red[4 + w] = ss; }
  __syncthreads();
  s  = red[0] + red[1] + red[2] + red[3];
  ss = red[4] + red[5] + red[6] + red[7];
  const float mean = s * (1.0f / E);
  const float var  = ss * (1.0f / E) - mean * mean;
  const float rstd = rsqrtf(var + 1e-5f);
  float4 gv = *(const float4*)&g[t * 4];
  float4 bv = *(const float4*)&be[t * 4];
  bf16x4 o;
  o[0] = (__bf16)((v.x - mean) * rstd * gv.x + bv.x);
  o[1] = (__bf16)((v.y - mean) * rstd * gv.y + bv.y);
  o[2] = (__bf16)((v.z - mean) * rstd * gv.z + bv.z);
  o[3] = (__bf16)((v.w - mean) * rstd * gv.w + bv.w);
  *(bf16x4*)&O[row * E + t * 4] = o;
}

// ---------------------------------------------------------------------------
// Reduce for split-K FF2: out = out(resid, in-place) + bias + tmp0 + tmp1.
// ---------------------------------------------------------------------------
__global__ __launch_bounds__(256) void reduce2_kernel(float* __restrict__ out,
                                                      const __bf16* __restrict__ t0,
                                                      const __bf16* __restrict__ t1,
                                                      const float* __restrict__ b2) {
  const int i = blockIdx.x * 256 + threadIdx.x;   // 2M groups of float4
  float4 o = ((const float4*)out)[i];
  bf16x4 a = ((const bf16x4*)t0)[i];
  bf16x4 b = ((const bf16x4*)t1)[i];
  float4 bb = ((const float4*)b2)[i & 255];
  o.x += bb.x + (float)a[0] + (float)b[0];
  o.y += bb.y + (float)a[1] + (float)b[1];
  o.z += bb.z + (float)a[2] + (float)b[2];
  o.w += bb.w + (float)a[3] + (float)b[3];
  ((float4*)out)[i] = o;
}

// ---------------------------------------------------------------------------
// m201-style 8-phase GEMM (4 phases per BK=64 K-tile, 2 tiles per dbuf pair).
// C[M][N] = op(A[M][K] @ Bt[N][K]^T + bias)(+resid). KLD = row stride.
// BM=BN=256. 512 threads = 8 waves (2 wr x 4 wc); per-wave out 128x64
// (rows m*32+wr*16, m=0..7; cols n*64+wc*16, n=0..3).
// LDS = 2 bufs x 4 units(Ah0,Ah1,Bh0,Bh1) x 16KB = 128 KB.
// Quadrant order Q1(m0-3,n0-1) Q2(m0-3,n2-3) Q3(m4-7,n0-1) Q4(m4-7,n2-3):
// each unit is read in exactly one phase -> slot free next phase.
// Stage schedule: ph1: Ah1(t+1); ph2: Ah0(t+2); ph3: Bh0(t+2); ph4: Bh1(t+2).
// avm<6> at ph4 leaves exactly the 3 newest units outstanding => tile t+1
// fully landed at its ph1 (ledger verified incl. prologue 4+3 units).
// Swizzle (128B rows, 8x16B pieces): piece ^= (row&7), both sides.
// ---------------------------------------------------------------------------
template <bool RELU, bool RESID, bool OUTBF, int NB>
__global__ __launch_bounds__(512, 2) void gemm8p_kernel(const __bf16* __restrict__ A,
                                                        const __bf16* __restrict__ Bt,
                                                        const float* __restrict__ bias0,
                                                        const float* __restrict__ bias1,
                                                        const float* __restrict__ bias2,
                                                        const float* resid,
                                                        void* Cout, void* Cout2,
                                                        int M, int N, int K, int KLD) {
  extern __shared__ char lds[];      // 131072 B
  const int tid  = threadIdx.x;
  const int lane = tid & 63;
  const int l15  = lane & 15;
  const int kp   = lane >> 4;        // 0..3
  const int wid  = tid >> 6;
  const int wr   = wid >> 2;         // 0..1
  const int wc   = wid & 3;          // 0..3

  // XCD-aware swizzle over full 3D grid (nwg % 8 == 0 everywhere)
  const int gx   = gridDim.x, gy = gridDim.y;
  const int nwg  = gx * gy * gridDim.z;
  const int flat = blockIdx.x + gx * (blockIdx.y + gy * blockIdx.z);
  const int swz  = (flat & 7) * (nwg >> 3) + (flat >> 3);
  const int bx   = swz % gx;
  const int by   = (swz / gx) % gy;
  const int bz   = swz / (gx * gy);
  const long brow = (long)by * 256;
  const long bcol = (long)bx * 256;
  const long koff = (long)bz * K;

  const __bf16* Ab = A  + brow * KLD + koff;
  const __bf16* Bb = Bt + bcol * KLD + koff;
  void* Cdst = bz ? Cout2 : Cout;
  const int NT = K >> 6;

  // stage one 16KB half-tile unit (128 rows/cols x 64 k); pre-swizzled source
  auto stageU = [&](const __bf16* Gb, int rc0, int k0, int dstOff) {
#pragma unroll
    for (int i = 0; i < 2; ++i) {
      const int c = i * 512 + tid;
      const int r = c >> 3;
      const int p = (c & 7) ^ (r & 7);
      gload16(Gb + (long)(rc0 + r) * KLD + k0 + p * 8, lds + dstOff + c * 16);
    }
  };

  f32x4 acc[8][4];
  const f32x4 z4 = {0.f, 0.f, 0.f, 0.f};
#pragma unroll
  for (int m = 0; m < 8; ++m)
#pragma unroll
    for (int n = 0; n < 4; ++n) acc[m][n] = z4;

  bf16x8 af[4][2], bh0[2][2], bh1[2][2];

  // A-frag read: local rows mm*32+wr*16+l15 within a half at LDS offset `off`
  auto readA = [&](int off) {
#pragma unroll
    for (int mm = 0; mm < 4; ++mm)
#pragma unroll
      for (int kk = 0; kk < 2; ++kk) {
        const int lr = mm * 32 + wr * 16 + l15;
        const int p  = ((kk << 2) + kp) ^ (lr & 7);
        af[mm][kk] = *(const bf16x8*)(lds + off + lr * 128 + p * 16);
      }
  };
  // B-frag read: local cols nn*64+wc*16+l15 within a half
  auto readB = [&](int off, bf16x8 (*bf)[2]) {
#pragma unroll
    for (int nn = 0; nn < 2; ++nn)
#pragma unroll
      for (int kk = 0; kk < 2; ++kk) {
        const int lc = nn * 64 + wc * 16 + l15;
        const int p  = ((kk << 2) + kp) ^ (lc & 7);
        bf[nn][kk] = *(const bf16x8*)(lds + off + lc * 128 + p * 16);
      }
  };
  auto quad = [&](int mb, int nb, bf16x8 (*bf)[2]) {
    __builtin_amdgcn_s_setprio(1);
#pragma unroll
    for (int mm = 0; mm < 4; ++mm)
#pragma unroll
      for (int nn = 0; nn < 2; ++nn) {
        f32x4 a = acc[mb + mm][nb + nn];
        a = __builtin_amdgcn_mfma_f32_16x16x32_bf16(af[mm][0], bf[nn][0], a, 0, 0, 0);
        a = __builtin_amdgcn_mfma_f32_16x16x32_bf16(af[mm][1], bf[nn][1], a, 0, 0, 0);
        acc[mb + mm][nb + nn] = a;
      }
    __builtin_amdgcn_s_setprio(0);
  };

  // ---- prologue: tile0 all 4 units + tile1's Ah0,Bh0,Bh1 (Ah1(1) staged in ph1(0))
  stageU(Ab, 0,   0, 0);                   // Ah0(0)
  stageU(Bb, 0,   0, 32768);               // Bh0(0)
  stageU(Bb, 128, 0, 49152);               // Bh1(0)
  stageU(Ab, 128, 0, 16384);               // Ah1(0)
  stageU(Ab, 0,   64, 65536 + 0);          // Ah0(1)
  stageU(Bb, 0,   64, 65536 + 32768);      // Bh0(1)
  stageU(Bb, 128, 64, 65536 + 49152);      // Bh1(1)
  avm<6>();   // drain tile0's 4 units (8 loads); tile1's 3 units stay in flight
  ABAR();

  for (int t = 0; t < NT; ++t) {
    const int cb  = (t & 1) ? 65536 : 0;        // current buf
    const int nb1 = cb ^ 65536;                 // buf of t+1
    const int k1 = (t + 1 < NT) ? ((t + 1) << 6) : 0;
    const int k2 = (t + 2 < NT) ? ((t + 2) << 6) : 0;

    // ph1: read Ah0 + Bh0; stage Ah1(t+1); MFMA Q1
    readA(cb + 0);
    readB(cb + 32768, bh0);
    stageU(Ab, 128, k1, nb1 + 16384);
    ABAR(); ALGKM0();
    quad(0, 0, bh0);
    ABAR();

    // ph2: read Bh1; stage Ah0(t+2) into freed Ah0 slot; MFMA Q2
    readB(cb + 49152, bh1);
    stageU(Ab, 0, k2, cb + 0);
    ABAR(); ALGKM0();
    quad(0, 2, bh1);
    ABAR();

    // ph3: read Ah1; stage Bh0(t+2); MFMA Q3
    readA(cb + 16384);
    stageU(Bb, 0, k2, cb + 32768);
    ABAR(); ALGKM0();
    quad(4, 0, bh0);
    ABAR();

    // ph4: stage Bh1(t+2); counted vmcnt; MFMA Q4 (all operands held)
    stageU(Bb, 128, k2, cb + 49152);
    avm<6>();
    ABAR();
    quad(4, 2, bh1);
    ABAR();
  }
  avm<0>();  // drain tail dummy stages

  // ---- epilogue. D layout: col=lane&15, row=(lane>>4)*4+j within frag ----
#pragma unroll
  for (int m = 0; m < 8; ++m) {
#pragma unroll
    for (int n = 0; n < 4; ++n) {
      const long col = bcol + n * 64 + wc * 16 + l15;
      float bb;
      if (NB == 3) {
        const float* bp = (col < 1024) ? bias0 : ((col < 2048) ? bias1 : bias2);
        bb = bp[col & 1023];
      } else if (NB == 1) {
        bb = bias0[col];
      } else {
        bb = 0.f;
      }
#pragma unroll
      for (int j = 0; j < 4; ++j) {
        const long row = brow + m * 32 + wr * 16 + (lane >> 4) * 4 + j;
        float val = acc[m][n][j] + bb;
        if (RELU) val = fmaxf(val, 0.f);
        const long idx = row * N + col;
        if (RESID) val += resid[idx];
        if (OUTBF) ((__bf16*)Cdst)[idx] = (__bf16)val;
        else       ((float*)Cdst)[idx]  = val;
      }
    }
  }
}

// ---------------------------------------------------------------------------
// BK=32 ring GEMM (R8) — kept for the O-projection (BM=128, N=1024, full chip).
// ---------------------------------------------------------------------------
template <int BM_, int DEPTH, bool RELU, bool RESID, bool OUTBF, int NB>
__global__ __launch_bounds__(512, 2) void gemmk_kernel(const __bf16* __restrict__ A,
                                                       const __bf16* __restrict__ Bt,
                                                       const float* __restrict__ bias0,
                                                       const float* __restrict__ bias1,
                                                       const float* __restrict__ bias2,
                                                       const float* resid,
                                                       void* Cout, void* Cout2,
                                                       int M, int N, int K, int KLD) {
  extern __shared__ char lds[];
  constexpr int MF    = BM_ / 32;
  constexpr int ABYT  = BM_ * 64;
  constexpr int TILEB = ABYT + 16384;
  constexpr int AL    = BM_ / 128;
  constexpr int TL    = AL + 2;
  constexpr int W     = (DEPTH - 2) * TL;

  const int tid  = threadIdx.x;
  const int lane = tid & 63;
  const int l15  = lane & 15;
  const int kp   = lane >> 4;
  const int wid  = tid >> 6;
  const int wr   = wid >> 2;
  const int wc   = wid & 3;

  const int gx   = gridDim.x, gy = gridDim.y;
  const int nwg  = gx * gy * gridDim.z;
  const int flat = blockIdx.x + gx * (blockIdx.y + gy * blockIdx.z);
  const int swz  = (flat & 7) * (nwg >> 3) + (flat >> 3);
  const int bx   = swz % gx;
  const int by   = (swz / gx) % gy;
  const int bz   = swz / (gx * gy);
  const long brow = (long)by * BM_;
  const long bcol = (long)bx * 256;
  const long koff = (long)bz * K;

  const __bf16* Ab = A  + brow * KLD + koff;
  const __bf16* Bb = Bt + bcol * KLD + koff;
  void* Cdst = bz ? Cout2 : Cout;
  const int NT = K >> 5;

  auto stageA = [&](int k0, char* dst) {
#pragma unroll
    for (int i = 0; i < AL; ++i) {
      const int c = i * 512 + tid;
      const int r = c >> 2;
      const int p = (c & 3) ^ ((r >> 1) & 3);
      gload16(Ab + (long)r * KLD + k0 + p * 8, dst + c * 16);
    }
  };
  auto stageB = [&](int k0, char* dst) {
#pragma unroll
    for (int i = 0; i < 2; ++i) {
      const int c = i * 512 + tid;
      const int r = c >> 2;
      const int p = (c & 3) ^ ((r >> 1) & 3);
      gload16(Bb + (long)r * KLD + k0 + p * 8, dst + c * 16);
    }
  };

  f32x4 acc[MF][4];
  const f32x4 z4 = {0.f, 0.f, 0.f, 0.f};
#pragma unroll
  for (int m = 0; m < MF; ++m)
#pragma unroll
    for (int n = 0; n < 4; ++n) acc[m][n] = z4;

#pragma unroll
  for (int pt = 0; pt < DEPTH - 1; ++pt) {
    stageA(pt * 32, lds + pt * TILEB);
    stageB(pt * 32, lds + pt * TILEB + ABYT);
  }

  bf16x8 af[4], bfr[4];

  for (int t = 0; t < NT; ++t) {
    const int cb = t % DEPTH;
    const int sb = (t + DEPTH - 1) % DEPTH;
    const char* Ac = lds + cb * TILEB;
    const char* Bc = Ac + ABYT;
    char* An = lds + sb * TILEB;
    const int kt = (t + DEPTH - 1 < NT) ? ((t + DEPTH - 1) << 5) : 0;

    avm<W>();
    ABAR();

#pragma unroll
    for (int m = 0; m < 4; ++m) {
      const int row = m * 32 + wr * 16 + l15;
      af[m] = *(const bf16x8*)(Ac + row * 64 + (kp ^ ((row >> 1) & 3)) * 16);
    }
#pragma unroll
    for (int n = 0; n < 4; ++n) {
      const int col = n * 64 + wc * 16 + l15;
      bfr[n] = *(const bf16x8*)(Bc + col * 64 + (kp ^ ((col >> 1) & 3)) * 16);
    }
    stageA(kt, An);
    stageB(kt, An + ABYT);
    ABAR(); ALGKM0();
    __builtin_amdgcn_s_setprio(1);
#pragma unroll
    for (int m = 0; m < 4; ++m)
#pragma unroll
      for (int n = 0; n < 4; ++n)
        acc[m][n] = __builtin_amdgcn_mfma_f32_16x16x32_bf16(af[m], bfr[n], acc[m][n], 0, 0, 0);
    __builtin_amdgcn_s_setprio(0);
  }
  avm<0>();

#pragma unroll
  for (int m = 0; m < MF; ++m) {
#pragma unroll
    for (int n = 0; n < 4; ++n) {
      const long col = bcol + n * 64 + wc * 16 + l15;
      float bb;
      if (NB == 3) {
        const float* bp = (col < 1024) ? bias0 : ((col < 2048) ? bias1 : bias2);
        bb = bp[col & 1023];
      } else if (NB == 1) {
        bb = bias0[col];
      } else {
        bb = 0.f;
      }
#pragma unroll
      for (int j = 0; j < 4; ++j) {
        const long row = brow + m * 32 + wr * 16 + (lane >> 4) * 4 + j;
        float val = acc[m][n][j] + bb;
        if (RELU) val = fmaxf(val, 0.f);
        const long idx = row * N + col;
        if (RESID) val += resid[idx];
        if (OUTBF) ((__bf16*)Cdst)[idx] = (__bf16)val;
        else       ((float*)Cdst)[idx]  = val;
      }
    }
  }
}

// ---------------------------------------------------------------------------
// Flash attention, swapped-operand 32x32 structure (m214-style). Unchanged.
// ---------------------------------------------------------------------------
__global__ __launch_bounds__(256, 3) void attn_kernel(const __bf16* __restrict__ QKV,
                                                      __bf16* __restrict__ Og) {
  __shared__ __align__(16) __bf16 Qs[128 * 64];    // 16KB [qrow][d]
  __shared__ __align__(16) __bf16 Ks[2][64 * 64];  // 2x8KB [key][d]
  __shared__ __align__(16) __bf16 Vt[2][64 * 64];  // 2x8KB [d][key]

  const int QSTR = 3072;
  const int t    = threadIdx.x;
  const int lane = t & 63;
  const int w    = t >> 6;       // wave 0..3
  const int l31  = lane & 31;
  const int h    = lane >> 5;    // half 0/1
  const int b    = blockIdx.y >> 4;
  const int hh   = blockIdx.y & 15;
  const long row0 = (long)b * 1024 + (long)blockIdx.x * 128;
  const long kvrow0 = (long)b * 1024;
  const int colQ = hh * 64;
  const int colK = colQ + 1024;
  const int colV = colQ + 2048;

  // ---- prologue: stage Q (once), K[0], V[0] ----
#pragma unroll
  for (int j = 0; j < 4; ++j) {
    const int c = j * 256 + t;
    const int r = c >> 3;
    const int p = (c & 7) ^ (r & 7);
    gload16(QKV + (row0 + r) * QSTR + colQ + p * 8, (char*)Qs + c * 16);
  }
#pragma unroll
  for (int j = 0; j < 2; ++j) {
    const int c = j * 256 + t;
    const int r = c >> 3;
    const int p = (c & 7) ^ (r & 7);
    gload16(QKV + (kvrow0 + r) * QSTR + colK + p * 8, (char*)Ks[0] + c * 16);
  }
  bf16x8 vv[2];
#pragma unroll
  for (int j = 0; j < 2; ++j) {
    const int c = j * 256 + t;
    const int key = c >> 3, dc = c & 7;
    vv[j] = *(const bf16x8*)(QKV + (kvrow0 + key) * QSTR + colV + dc * 8);
  }
  AVM(0);
#pragma unroll
  for (int j = 0; j < 2; ++j) {
    const int c = j * 256 + t;
    const int key = c >> 3, dc = c & 7;
#pragma unroll
    for (int e = 0; e < 8; ++e) {
      const int d = dc * 8 + e;
      *(__bf16*)((char*)Vt[0] + d * 128 + (((key >> 3) ^ dc) * 16) + (key & 7) * 2) = vv[j][e];
    }
  }
  __syncthreads();

  // hoist Q fragments (B-operand: col=q=l31, k-chunk = kk*16 + h*8)
  bf16x8 bq[4];
  {
    const int qrow = w * 32 + l31;
#pragma unroll
    for (int kk = 0; kk < 4; ++kk) {
      const int p = (kk * 2 + h) ^ (qrow & 7);
      bq[kk] = *(const bf16x8*)((const char*)Qs + qrow * 128 + p * 16);
    }
  }

  f32x16 ctx0, ctx1;
#pragma unroll
  for (int r = 0; r < 16; ++r) { ctx0[r] = 0.f; ctx1[r] = 0.f; }
  float m = -INFINITY, l = 0.f;

  for (int kb = 0; kb < 16; ++kb) {
    const int cur = kb & 1, nxt = cur ^ 1;
    const int kb1 = (kb + 1 < 16) ? kb + 1 : kb;
    const long kr1 = kvrow0 + kb1 * 64;

    // prefetch next tile: V reg-loads first, then K global->LDS
#pragma unroll
    for (int j = 0; j < 2; ++j) {
      const int c = j * 256 + t;
      const int key = c >> 3, dc = c & 7;
      vv[j] = *(const bf16x8*)(QKV + (kr1 + key) * QSTR + colV + dc * 8);
    }
#pragma unroll
    for (int j = 0; j < 2; ++j) {
      const int c = j * 256 + t;
      const int r = c >> 3;
      const int p = (c & 7) ^ (r & 7);
      gload16(QKV + (kr1 + r) * QSTR + colK + p * 8, (char*)Ks[nxt] + c * 16);
    }

    // ---- QK^T swapped: A=K rows(keys), B=Q cols(q) ----
    f32x16 s0, s1;
#pragma unroll
    for (int r = 0; r < 16; ++r) { s0[r] = 0.f; s1[r] = 0.f; }
    __builtin_amdgcn_s_setprio(1);
#pragma unroll
    for (int kk = 0; kk < 4; ++kk) {
      const int pce = kk * 2 + h;
      const int p0i = pce ^ (l31 & 7);
      bf16x8 ak0 = *(const bf16x8*)((const char*)Ks[cur] + l31 * 128 + p0i * 16);
      bf16x8 ak1 = *(const bf16x8*)((const char*)Ks[cur] + (32 + l31) * 128 + p0i * 16);
      s0 = __builtin_amdgcn_mfma_f32_32x32x16_bf16(ak0, bq[kk], s0, 0, 0, 0);
      s1 = __builtin_amdgcn_mfma_f32_32x32x16_bf16(ak1, bq[kk], s1, 0, 0, 0);
    }
    __builtin_amdgcn_s_setprio(0);

    // ---- in-register online softmax (raw units; scale 1/8 folded into exp) ----
    float mx = s0[0];
#pragma unroll
    for (int r = 1; r < 16; ++r) mx = fmaxf(mx, s0[r]);
#pragma unroll
    for (int r = 0; r < 16; ++r) mx = fmaxf(mx, s1[r]);
    mx = fmaxf(mx, __shfl_xor(mx, 32));

    if (!__all(mx - m <= 64.f)) {   // defer-max THR = 8 (x8 raw)
      const float mn = fmaxf(m, mx);
      const float corr = __expf((m - mn) * 0.125f);
      l *= corr;
#pragma unroll
      for (int r = 0; r < 16; ++r) { ctx0[r] *= corr; ctx1[r] *= corr; }
      m = mn;
    }
    f32x16 p0, p1;
    float rs = 0.f;
#pragma unroll
    for (int r = 0; r < 16; ++r) { p0[r] = __expf((s0[r] - m) * 0.125f); rs += p0[r]; }
#pragma unroll
    for (int r = 0; r < 16; ++r) { p1[r] = __expf((s1[r] - m) * 0.125f); rs += p1[r]; }
    rs += __shfl_xor(rs, 32);
    l += rs;

    // ---- write V[t+1] transpose into Vt[nxt] ----
    AVM(2);
#pragma unroll
    for (int j = 0; j < 2; ++j) {
      const int c = j * 256 + t;
      const int key = c >> 3, dc = c & 7;
#pragma unroll
      for (int e = 0; e < 8; ++e) {
        const int d = dc * 8 + e;
        *(__bf16*)((char*)Vt[nxt] + d * 128 + (((key >> 3) ^ dc) * 16) + (key & 7) * 2) = vv[j][e];
      }
    }

    // ---- build PV B-operand frags: pa[ks][e] = P[k=ks*16+h*8+e][q] ----
    bf16x8 paf[4];
#pragma unroll
    for (int ks = 0; ks < 4; ++ks) {
      const int base = (ks & 1) * 8;
      unsigned a0, a1, b0, b1;
      if (ks < 2) {
        CVTPK(a0, p0[base + 0], p0[base + 1]);
        CVTPK(b0, p0[base + 4], p0[base + 5]);
        CVTPK(a1, p0[base + 2], p0[base + 3]);
        CVTPK(b1, p0[base + 6], p0[base + 7]);
      } else {
        CVTPK(a0, p1[base + 0], p1[base + 1]);
        CVTPK(b0, p1[base + 4], p1[base + 5]);
        CVTPK(a1, p1[base + 2], p1[base + 3]);
        CVTPK(b1, p1[base + 6], p1[base + 7]);
      }
      PLSWAP(a0, b0);
      PLSWAP(a1, b1);
      u32x4 wv4; wv4[0] = a0; wv4[1] = a1; wv4[2] = b0; wv4[3] = b1;
      paf[ks] = __builtin_bit_cast(bf16x8, wv4);
    }

    // ---- PV swapped: ctx(O^T) += mfma(A=Vt rows(d), B=P cols(q)) ----
    __builtin_amdgcn_s_setprio(1);
#pragma unroll
    for (int ks = 0; ks < 4; ++ks) {
      const int pce = ks * 2 + h;
      bf16x8 av0 = *(const bf16x8*)((const char*)Vt[cur] + l31 * 128 + ((pce ^ (l31 >> 3)) * 16));
      bf16x8 av1 = *(const bf16x8*)((const char*)Vt[cur] + (32 + l31) * 128 + ((pce ^ (4 + (l31 >> 3))) * 16));
      ctx0 = __builtin_amdgcn_mfma_f32_32x32x16_bf16(av0, paf[ks], ctx0, 0, 0, 0);
      ctx1 = __builtin_amdgcn_mfma_f32_32x32x16_bf16(av1, paf[ks], ctx1, 0, 0, 0);
    }
    __builtin_amdgcn_s_setprio(0);

    __syncthreads();
  }

  // ---- epilogue: O[q][d] = ctx^T / l ----
  const float inv = 1.0f / l;
  const long orow = row0 + w * 32 + l31;
#pragma unroll
  for (int f = 0; f < 2; ++f)
#pragma unroll
    for (int tq = 0; tq < 4; ++tq) {
      bf16x4 o;
#pragma unroll
      for (int e = 0; e < 4; ++e) {
        const float v = (f ? ctx1[tq * 4 + e] : ctx0[tq * 4 + e]) * inv;
        o[e] = (__bf16)v;
      }
      const int col = colQ + f * 32 + tq * 8 + h * 4;
      *(bf16x4*)&Og[orow * E + col] = o;
    }
}

// ---------------------------------------------------------------------------
extern "C" void kernel_launch(void* const* d_in, const int* in_sizes, int n_in,
                              void* d_out, int out_size, void* d_ws, size_t ws_size,
                              hipStream_t stream) {
  const float* x     = (const float*)d_in[0];
  const float* ln1g  = (const float*)d_in[1];
  const float* ln1b  = (const float*)d_in[2];
  const float* ln2g  = (const float*)d_in[3];
  const float* ln2b  = (const float*)d_in[4];
  const float* wq    = (const float*)d_in[5];
  const float* bq    = (const float*)d_in[6];
  const float* wk    = (const float*)d_in[7];
  const float* bk    = (const float*)d_in[8];
  const float* wv    = (const float*)d_in[9];
  const float* bv    = (const float*)d_in[10];
  const float* wo    = (const float*)d_in[11];
  const float* bo    = (const float*)d_in[12];
  const float* w1    = (const float*)d_in[13];
  const float* b1    = (const float*)d_in[14];
  const float* w2    = (const float*)d_in[15];
  const float* b2    = (const float*)d_in[16];
  float* out = (float*)d_out;

  char* ws = (char*)d_ws;
  const size_t MB = 1024 * 1024;
  __bf16* Wqkv = (__bf16*)(ws + 0 * MB);    // [3072][1024] bf16, 6MB
  __bf16* Wot  = (__bf16*)(ws + 6 * MB);    // [1024][1024] 2MB
  __bf16* W1t  = (__bf16*)(ws + 8 * MB);    // [4096][1024] 8MB
  __bf16* W2t  = (__bf16*)(ws + 16 * MB);   // [1024][4096] 8MB
  __bf16* h    = (__bf16*)(ws + 24 * MB);   // [8192][1024] 16MB
  __bf16* qkv  = (__bf16*)(ws + 40 * MB);   // [8192][3072] 48MB
  __bf16* ctx  = (__bf16*)(ws + 88 * MB);   // [8192][1024] 16MB
  __bf16* ff1  = (__bf16*)(ws + 40 * MB);   // [8192][4096] 64MB, aliases qkv
  __bf16* tmp0 = (__bf16*)(ws + 0 * MB);    // FF2 partial 0 (weights dead)
  __bf16* tmp1 = (__bf16*)(ws + 24 * MB);   // FF2 partial 1 (h dead)

  const dim3 blk(256);
  const dim3 blk512(512);
  const size_t GLDS8P  = 131072;                 // 2 bufs x 64KB
  const size_t GLDS128 = 5 * (128 * 64 + 16384); // 120 KB, DEPTH=5

  wconv_kernel<<<dim3(E / 32, E / 32), blk, 0, stream>>>(wq, Wqkv, E, E);
  wconv_kernel<<<dim3(E / 32, E / 32), blk, 0, stream>>>(wk, Wqkv + 1024 * 1024, E, E);
  wconv_kernel<<<dim3(E / 32, E / 32), blk, 0, stream>>>(wv, Wqkv + 2048 * 1024, E, E);
  wconv_kernel<<<dim3(E / 32, E / 32), blk, 0, stream>>>(wo, Wot, E, E);
  wconv_kernel<<<dim3(HID / 32, E / 32), blk, 0, stream>>>(w1, W1t, E, HID);
  wconv_kernel<<<dim3(E / 32, HID / 32), blk, 0, stream>>>(w2, W2t, HID, E);

  // LN1
  ln_kernel<<<TOK, blk, 0, stream>>>(x, ln1g, ln1b, h);

  // fused QKV projection: [8192][3072]   grid 12x32 = 384 blocks
  gemm8p_kernel<false, false, true, 3><<<dim3(3072 / 256, TOK / 256), blk512, GLDS8P, stream>>>(
      h, Wqkv, bq, bk, bv, nullptr, qkv, nullptr, TOK, 3072, E, E);

  // attention: 8 q-blocks of 128 rows x 128 (b,h)
  attn_kernel<<<dim3(8, 128), blk, 0, stream>>>(qkv, ctx);

  // O projection + residual(x) -> d_out (fp32)   grid 4x64 = 256 blocks
  gemmk_kernel<128, 5, false, true, false, 1><<<dim3(E / 256, TOK / 128), blk512, GLDS128, stream>>>(
      ctx, Wot, bo, nullptr, nullptr, x, out, nullptr, TOK, E, E, E);

  // LN2 on d_out
  ln_kernel<<<TOK, blk, 0, stream>>>(out, ln2g, ln2b, h);

  // FF1 with ReLU -> ff1 (bf16)   grid 16x32 = 512 blocks
  gemm8p_kernel<true, false, true, 1><<<dim3(HID / 256, TOK / 256), blk512, GLDS8P, stream>>>(
      h, W1t, b1, nullptr, nullptr, nullptr, ff1, nullptr, TOK, HID, E, E);

  // FF2 split-K=2: partials -> tmp0/tmp1   grid 4x32x2 = 256 blocks
  gemm8p_kernel<false, false, true, 0><<<dim3(E / 256, TOK / 256, 2), blk512, GLDS8P, stream>>>(
      ff1, W2t, nullptr, nullptr, nullptr, nullptr, tmp0, tmp1, TOK, E, HID / 2, HID);

  // reduce: out = out(resid) + b2 + tmp0 + tmp1
  reduce2_kernel<<<TOK * E / 1024, blk, 0, stream>>>(out, tmp0, tmp1, b2);
}

// Round 10
// 347.926 us; speedup vs baseline: 1.0550x; 1.0305x over previous
//
#include <hip/hip_runtime.h>
#include <hip/hip_bf16.h>

typedef __attribute__((ext_vector_type(4))) float f32x4;
typedef __attribute__((ext_vector_type(16))) float f32x16;
typedef __attribute__((ext_vector_type(8))) __bf16 bf16x8;
typedef __attribute__((ext_vector_type(4))) __bf16 bf16x4;
typedef __attribute__((ext_vector_type(4))) unsigned int u32x4;

static constexpr int E    = 1024;
static constexpr int TOK  = 8192;   // 8 * 1024 tokens
static constexpr int HID  = 4096;

#define DEVINL __device__ __forceinline__

// async global->LDS, 16B per lane. LDS dest must be lane-linear (wave base + lane*16).
DEVINL void gload16(const void* g, void* l) {
  __builtin_amdgcn_global_load_lds((__attribute__((address_space(1))) void*)g,
                                   (__attribute__((address_space(3))) void*)l, 16, 0, 0);
}

#define ABAR()  asm volatile("s_barrier" ::: "memory")
#define AVM(n)  asm volatile("s_waitcnt vmcnt(" #n ")" ::: "memory")
// bare hint — NO sched_barrier (m141: order-pinning poisons the scheduler),
// no memory clobber (C++ ds_reads get compiler-tracked waitcnts anyway).
#define ALGKM0() asm volatile("s_waitcnt lgkmcnt(0)")
#define CVTPK(dst, lo, hi) asm("v_cvt_pk_bf16_f32 %0, %1, %2" : "=v"(dst) : "v"(lo), "v"(hi))
#define PLSWAP(a, b) asm("v_permlane32_swap_b32 %0, %1" : "+v"(a), "+v"(b))

template <int N> DEVINL void avm() {
  if constexpr (N == 0)      asm volatile("s_waitcnt vmcnt(0)" ::: "memory");
  else if constexpr (N == 2) asm volatile("s_waitcnt vmcnt(2)" ::: "memory");
  else if constexpr (N == 6) asm volatile("s_waitcnt vmcnt(6)" ::: "memory");
  else if constexpr (N == 8) asm volatile("s_waitcnt vmcnt(8)" ::: "memory");
  else if constexpr (N == 9) asm volatile("s_waitcnt vmcnt(9)" ::: "memory");
  else                       asm volatile("s_waitcnt vmcnt(0)" ::: "memory");
}

// ---------------------------------------------------------------------------
// Merged weight convert+transpose: all 6 weights in ONE launch.
// W[K][N] f32 -> Wt[N][K] bf16, 32x32 LDS tiles. Segment by flat block id.
// ---------------------------------------------------------------------------
__global__ __launch_bounds__(256) void wconv6_kernel(const float* __restrict__ wq,
                                                     const float* __restrict__ wk,
                                                     const float* __restrict__ wv,
                                                     const float* __restrict__ wo,
                                                     const float* __restrict__ w1,
                                                     const float* __restrict__ w2,
                                                     __bf16* __restrict__ Wqkv,
                                                     __bf16* __restrict__ Wot,
                                                     __bf16* __restrict__ W1t,
                                                     __bf16* __restrict__ W2t) {
  const int id = blockIdx.x;
  const float* W; __bf16* Wt; int K, N, lid;
  if (id < 1024)      { W = wq; Wt = Wqkv;                K = 1024; N = 1024; lid = id; }
  else if (id < 2048) { W = wk; Wt = Wqkv + 1024 * 1024;  K = 1024; N = 1024; lid = id - 1024; }
  else if (id < 3072) { W = wv; Wt = Wqkv + 2048 * 1024;  K = 1024; N = 1024; lid = id - 2048; }
  else if (id < 4096) { W = wo; Wt = Wot;                 K = 1024; N = 1024; lid = id - 3072; }
  else if (id < 8192) { W = w1; Wt = W1t;                 K = 1024; N = 4096; lid = id - 4096; }
  else                { W = w2; Wt = W2t;                 K = 4096; N = 1024; lid = id - 8192; }
  const int nx = N >> 5;
  const long n0 = (long)(lid % nx) * 32;
  const long k0 = (long)(lid / nx) * 32;

  __shared__ float tile[32][33];
  const int t  = threadIdx.x;
  const int r  = t >> 3;
  const int c4 = (t & 7) * 4;
  float4 v = *(const float4*)&W[(k0 + r) * N + n0 + c4];
  tile[r][c4 + 0] = v.x; tile[r][c4 + 1] = v.y;
  tile[r][c4 + 2] = v.z; tile[r][c4 + 3] = v.w;
  __syncthreads();
  bf16x4 o;
#pragma unroll
  for (int i = 0; i < 4; ++i) o[i] = (__bf16)tile[c4 + i][r];
  *(bf16x4*)&Wt[(n0 + r) * K + k0 + c4] = o;
}

// ---------------------------------------------------------------------------
// LayerNorm (fp32 in) -> bf16 out. One block per row of 1024.
// ---------------------------------------------------------------------------
__global__ __launch_bounds__(256) void ln_kernel(const float* __restrict__ X,
                                                 const float* __restrict__ g,
                                                 const float* __restrict__ be,
                                                 __bf16* __restrict__ O) {
  const int t = threadIdx.x;
  const long row = blockIdx.x;
  float4 v = *(const float4*)&X[row * E + t * 4];
  float s  = v.x + v.y + v.z + v.w;
  float ss = v.x * v.x + v.y * v.y + v.z * v.z + v.w * v.w;
#pragma unroll
  for (int off = 32; off; off >>= 1) {
    s  += __shfl_down(s, off);
    ss += __shfl_down(ss, off);
  }
  __shared__ float red[8];
  const int w = t >> 6;
  if ((t & 63) == 0) { red[w] = s; red[4 + w] = ss; }
  __syncthreads();
  s  = red[0] + red[1] + red[2] + red[3];
  ss = red[4] + red[5] + red[6] + red[7];
  const float mean = s * (1.0f / E);
  const float var  = ss * (1.0f / E) - mean * mean;
  const float rstd = rsqrtf(var + 1e-5f);
  float4 gv = *(const float4*)&g[t * 4];
  float4 bv = *(const float4*)&be[t * 4];
  bf16x4 o;
  o[0] = (__bf16)((v.x - mean) * rstd * gv.x + bv.x);
  o[1] = (__bf16)((v.y - mean) * rstd * gv.y + bv.y);
  o[2] = (__bf16)((v.z - mean) * rstd * gv.z + bv.z);
  o[3] = (__bf16)((v.w - mean) * rstd * gv.w + bv.w);
  *(bf16x4*)&O[row * E + t * 4] = o;
}

// ---------------------------------------------------------------------------
// Reduce for split-K FF2: out = out(resid, in-place) + bias + tmp0 + tmp1.
// ---------------------------------------------------------------------------
__global__ __launch_bounds__(256) void reduce2_kernel(float* __restrict__ out,
                                                      const __bf16* __restrict__ t0,
                                                      const __bf16* __restrict__ t1,
                                                      const float* __restrict__ b2) {
  const int i = blockIdx.x * 256 + threadIdx.x;   // 2M groups of float4
  float4 o = ((const float4*)out)[i];
  bf16x4 a = ((const bf16x4*)t0)[i];
  bf16x4 b = ((const bf16x4*)t1)[i];
  float4 bb = ((const float4*)b2)[i & 255];
  o.x += bb.x + (float)a[0] + (float)b[0];
  o.y += bb.y + (float)a[1] + (float)b[1];
  o.z += bb.z + (float)a[2] + (float)b[2];
  o.w += bb.w + (float)a[3] + (float)b[3];
  ((float4*)out)[i] = o;
}

// ---------------------------------------------------------------------------
// m201-style 8-phase GEMM (4 phases per BK=64 K-tile, 2 tiles per dbuf pair).
// Same structure as R9; changes: bare lgkmcnt(0) (no sched_barrier),
// kk-outer MFMA order (no dependent back-to-back pairs on one acc).
// ---------------------------------------------------------------------------
template <bool RELU, bool RESID, bool OUTBF, int NB>
__global__ __launch_bounds__(512, 2) void gemm8p_kernel(const __bf16* __restrict__ A,
                                                        const __bf16* __restrict__ Bt,
                                                        const float* __restrict__ bias0,
                                                        const float* __restrict__ bias1,
                                                        const float* __restrict__ bias2,
                                                        const float* resid,
                                                        void* Cout, void* Cout2,
                                                        int M, int N, int K, int KLD) {
  extern __shared__ char lds[];      // 131072 B
  const int tid  = threadIdx.x;
  const int lane = tid & 63;
  const int l15  = lane & 15;
  const int kp   = lane >> 4;        // 0..3
  const int wid  = tid >> 6;
  const int wr   = wid >> 2;         // 0..1
  const int wc   = wid & 3;          // 0..3

  // XCD-aware swizzle over full 3D grid (nwg % 8 == 0 everywhere)
  const int gx   = gridDim.x, gy = gridDim.y;
  const int nwg  = gx * gy * gridDim.z;
  const int flat = blockIdx.x + gx * (blockIdx.y + gy * blockIdx.z);
  const int swz  = (flat & 7) * (nwg >> 3) + (flat >> 3);
  const int bx   = swz % gx;
  const int by   = (swz / gx) % gy;
  const int bz   = swz / (gx * gy);
  const long brow = (long)by * 256;
  const long bcol = (long)bx * 256;
  const long koff = (long)bz * K;

  const __bf16* Ab = A  + brow * KLD + koff;
  const __bf16* Bb = Bt + bcol * KLD + koff;
  void* Cdst = bz ? Cout2 : Cout;
  const int NT = K >> 6;

  // stage one 16KB half-tile unit (128 rows/cols x 64 k); pre-swizzled source
  auto stageU = [&](const __bf16* Gb, int rc0, int k0, int dstOff) {
#pragma unroll
    for (int i = 0; i < 2; ++i) {
      const int c = i * 512 + tid;
      const int r = c >> 3;
      const int p = (c & 7) ^ (r & 7);
      gload16(Gb + (long)(rc0 + r) * KLD + k0 + p * 8, lds + dstOff + c * 16);
    }
  };

  f32x4 acc[8][4];
  const f32x4 z4 = {0.f, 0.f, 0.f, 0.f};
#pragma unroll
  for (int m = 0; m < 8; ++m)
#pragma unroll
    for (int n = 0; n < 4; ++n) acc[m][n] = z4;

  bf16x8 af[4][2], bh0[2][2], bh1[2][2];

  auto readA = [&](int off) {
#pragma unroll
    for (int mm = 0; mm < 4; ++mm)
#pragma unroll
      for (int kk = 0; kk < 2; ++kk) {
        const int lr = mm * 32 + wr * 16 + l15;
        const int p  = ((kk << 2) + kp) ^ (lr & 7);
        af[mm][kk] = *(const bf16x8*)(lds + off + lr * 128 + p * 16);
      }
  };
  auto readB = [&](int off, bf16x8 (*bf)[2]) {
#pragma unroll
    for (int nn = 0; nn < 2; ++nn)
#pragma unroll
      for (int kk = 0; kk < 2; ++kk) {
        const int lc = nn * 64 + wc * 16 + l15;
        const int p  = ((kk << 2) + kp) ^ (lc & 7);
        bf[nn][kk] = *(const bf16x8*)(lds + off + lc * 128 + p * 16);
      }
  };
  // kk-outer: consecutive MFMAs hit different accumulators (no RAW chains)
  auto quad = [&](int mb, int nb, bf16x8 (*bf)[2]) {
    __builtin_amdgcn_s_setprio(1);
#pragma unroll
    for (int kk = 0; kk < 2; ++kk)
#pragma unroll
      for (int mm = 0; mm < 4; ++mm)
#pragma unroll
        for (int nn = 0; nn < 2; ++nn)
          acc[mb + mm][nb + nn] = __builtin_amdgcn_mfma_f32_16x16x32_bf16(
              af[mm][kk], bf[nn][kk], acc[mb + mm][nb + nn], 0, 0, 0);
    __builtin_amdgcn_s_setprio(0);
  };

  // ---- prologue: tile0 all 4 units + tile1's Ah0,Bh0,Bh1 (Ah1(1) staged in ph1(0))
  stageU(Ab, 0,   0, 0);                   // Ah0(0)
  stageU(Bb, 0,   0, 32768);               // Bh0(0)
  stageU(Bb, 128, 0, 49152);               // Bh1(0)
  stageU(Ab, 128, 0, 16384);               // Ah1(0)
  stageU(Ab, 0,   64, 65536 + 0);          // Ah0(1)
  stageU(Bb, 0,   64, 65536 + 32768);      // Bh0(1)
  stageU(Bb, 128, 64, 65536 + 49152);      // Bh1(1)
  avm<6>();   // drain tile0's 4 units; tile1's 3 units stay in flight
  ABAR();

  for (int t = 0; t < NT; ++t) {
    const int cb  = (t & 1) ? 65536 : 0;        // current buf
    const int nb1 = cb ^ 65536;                 // buf of t+1
    const int k1 = (t + 1 < NT) ? ((t + 1) << 6) : 0;
    const int k2 = (t + 2 < NT) ? ((t + 2) << 6) : 0;

    // ph1: read Ah0 + Bh0; stage Ah1(t+1); MFMA Q1
    readA(cb + 0);
    readB(cb + 32768, bh0);
    stageU(Ab, 128, k1, nb1 + 16384);
    ABAR(); ALGKM0();
    quad(0, 0, bh0);
    ABAR();

    // ph2: read Bh1; stage Ah0(t+2) into freed Ah0 slot; MFMA Q2
    readB(cb + 49152, bh1);
    stageU(Ab, 0, k2, cb + 0);
    ABAR(); ALGKM0();
    quad(0, 2, bh1);
    ABAR();

    // ph3: read Ah1; stage Bh0(t+2); MFMA Q3
    readA(cb + 16384);
    stageU(Bb, 0, k2, cb + 32768);
    ABAR(); ALGKM0();
    quad(4, 0, bh0);
    ABAR();

    // ph4: stage Bh1(t+2); counted vmcnt; MFMA Q4 (all operands held)
    stageU(Bb, 128, k2, cb + 49152);
    avm<6>();
    ABAR();
    quad(4, 2, bh1);
    ABAR();
  }
  avm<0>();  // drain tail dummy stages

  // ---- epilogue. D layout: col=lane&15, row=(lane>>4)*4+j within frag ----
#pragma unroll
  for (int m = 0; m < 8; ++m) {
#pragma unroll
    for (int n = 0; n < 4; ++n) {
      const long col = bcol + n * 64 + wc * 16 + l15;
      float bb;
      if (NB == 3) {
        const float* bp = (col < 1024) ? bias0 : ((col < 2048) ? bias1 : bias2);
        bb = bp[col & 1023];
      } else if (NB == 1) {
        bb = bias0[col];
      } else {
        bb = 0.f;
      }
#pragma unroll
      for (int j = 0; j < 4; ++j) {
        const long row = brow + m * 32 + wr * 16 + (lane >> 4) * 4 + j;
        float val = acc[m][n][j] + bb;
        if (RELU) val = fmaxf(val, 0.f);
        const long idx = row * N + col;
        if (RESID) val += resid[idx];
        if (OUTBF) ((__bf16*)Cdst)[idx] = (__bf16)val;
        else       ((float*)Cdst)[idx]  = val;
      }
    }
  }
}

// ---------------------------------------------------------------------------
// BK=32 ring GEMM — O-projection (BM=128, N=1024, full chip). Bare lgkm0.
// ---------------------------------------------------------------------------
template <int BM_, int DEPTH, bool RELU, bool RESID, bool OUTBF, int NB>
__global__ __launch_bounds__(512, 2) void gemmk_kernel(const __bf16* __restrict__ A,
                                                       const __bf16* __restrict__ Bt,
                                                       const float* __restrict__ bias0,
                                                       const float* __restrict__ bias1,
                                                       const float* __restrict__ bias2,
                                                       const float* resid,
                                                       void* Cout, void* Cout2,
                                                       int M, int N, int K, int KLD) {
  extern __shared__ char lds[];
  constexpr int MF    = BM_ / 32;
  constexpr int ABYT  = BM_ * 64;
  constexpr int TILEB = ABYT + 16384;
  constexpr int AL    = BM_ / 128;
  constexpr int TL    = AL + 2;
  constexpr int W     = (DEPTH - 2) * TL;

  const int tid  = threadIdx.x;
  const int lane = tid & 63;
  const int l15  = lane & 15;
  const int kp   = lane >> 4;
  const int wid  = tid >> 6;
  const int wr   = wid >> 2;
  const int wc   = wid & 3;

  const int gx   = gridDim.x, gy = gridDim.y;
  const int nwg  = gx * gy * gridDim.z;
  const int flat = blockIdx.x + gx * (blockIdx.y + gy * blockIdx.z);
  const int swz  = (flat & 7) * (nwg >> 3) + (flat >> 3);
  const int bx   = swz % gx;
  const int by   = (swz / gx) % gy;
  const int bz   = swz / (gx * gy);
  const long brow = (long)by * BM_;
  const long bcol = (long)bx * 256;
  const long koff = (long)bz * K;

  const __bf16* Ab = A  + brow * KLD + koff;
  const __bf16* Bb = Bt + bcol * KLD + koff;
  void* Cdst = bz ? Cout2 : Cout;
  const int NT = K >> 5;

  auto stageA = [&](int k0, char* dst) {
#pragma unroll
    for (int i = 0; i < AL; ++i) {
      const int c = i * 512 + tid;
      const int r = c >> 2;
      const int p = (c & 3) ^ ((r >> 1) & 3);
      gload16(Ab + (long)r * KLD + k0 + p * 8, dst + c * 16);
    }
  };
  auto stageB = [&](int k0, char* dst) {
#pragma unroll
    for (int i = 0; i < 2; ++i) {
      const int c = i * 512 + tid;
      const int r = c >> 2;
      const int p = (c & 3) ^ ((r >> 1) & 3);
      gload16(Bb + (long)r * KLD + k0 + p * 8, dst + c * 16);
    }
  };

  f32x4 acc[MF][4];
  const f32x4 z4 = {0.f, 0.f, 0.f, 0.f};
#pragma unroll
  for (int m = 0; m < MF; ++m)
#pragma unroll
    for (int n = 0; n < 4; ++n) acc[m][n] = z4;

#pragma unroll
  for (int pt = 0; pt < DEPTH - 1; ++pt) {
    stageA(pt * 32, lds + pt * TILEB);
    stageB(pt * 32, lds + pt * TILEB + ABYT);
  }

  bf16x8 af[4], bfr[4];

  for (int t = 0; t < NT; ++t) {
    const int cb = t % DEPTH;
    const int sb = (t + DEPTH - 1) % DEPTH;
    const char* Ac = lds + cb * TILEB;
    const char* Bc = Ac + ABYT;
    char* An = lds + sb * TILEB;
    const int kt = (t + DEPTH - 1 < NT) ? ((t + DEPTH - 1) << 5) : 0;

    avm<W>();
    ABAR();

#pragma unroll
    for (int m = 0; m < 4; ++m) {
      const int row = m * 32 + wr * 16 + l15;
      af[m] = *(const bf16x8*)(Ac + row * 64 + (kp ^ ((row >> 1) & 3)) * 16);
    }
#pragma unroll
    for (int n = 0; n < 4; ++n) {
      const int col = n * 64 + wc * 16 + l15;
      bfr[n] = *(const bf16x8*)(Bc + col * 64 + (kp ^ ((col >> 1) & 3)) * 16);
    }
    stageA(kt, An);
    stageB(kt, An + ABYT);
    ABAR(); ALGKM0();
    __builtin_amdgcn_s_setprio(1);
#pragma unroll
    for (int m = 0; m < 4; ++m)
#pragma unroll
      for (int n = 0; n < 4; ++n)
        acc[m][n] = __builtin_amdgcn_mfma_f32_16x16x32_bf16(af[m], bfr[n], acc[m][n], 0, 0, 0);
    __builtin_amdgcn_s_setprio(0);
  }
  avm<0>();

#pragma unroll
  for (int m = 0; m < MF; ++m) {
#pragma unroll
    for (int n = 0; n < 4; ++n) {
      const long col = bcol + n * 64 + wc * 16 + l15;
      float bb;
      if (NB == 3) {
        const float* bp = (col < 1024) ? bias0 : ((col < 2048) ? bias1 : bias2);
        bb = bp[col & 1023];
      } else if (NB == 1) {
        bb = bias0[col];
      } else {
        bb = 0.f;
      }
#pragma unroll
      for (int j = 0; j < 4; ++j) {
        const long row = brow + m * 32 + wr * 16 + (lane >> 4) * 4 + j;
        float val = acc[m][n][j] + bb;
        if (RELU) val = fmaxf(val, 0.f);
        const long idx = row * N + col;
        if (RESID) val += resid[idx];
        if (OUTBF) ((__bf16*)Cdst)[idx] = (__bf16)val;
        else       ((float*)Cdst)[idx]  = val;
      }
    }
  }
}

// ---------------------------------------------------------------------------
// Flash attention, swapped-operand 32x32 structure (m214-style). Unchanged.
// ---------------------------------------------------------------------------
__global__ __launch_bounds__(256, 3) void attn_kernel(const __bf16* __restrict__ QKV,
                                                      __bf16* __restrict__ Og) {
  __shared__ __align__(16) __bf16 Qs[128 * 64];    // 16KB [qrow][d]
  __shared__ __align__(16) __bf16 Ks[2][64 * 64];  // 2x8KB [key][d]
  __shared__ __align__(16) __bf16 Vt[2][64 * 64];  // 2x8KB [d][key]

  const int QSTR = 3072;
  const int t    = threadIdx.x;
  const int lane = t & 63;
  const int w    = t >> 6;       // wave 0..3
  const int l31  = lane & 31;
  const int h    = lane >> 5;    // half 0/1
  const int b    = blockIdx.y >> 4;
  const int hh   = blockIdx.y & 15;
  const long row0 = (long)b * 1024 + (long)blockIdx.x * 128;
  const long kvrow0 = (long)b * 1024;
  const int colQ = hh * 64;
  const int colK = colQ + 1024;
  const int colV = colQ + 2048;

  // ---- prologue: stage Q (once), K[0], V[0] ----
#pragma unroll
  for (int j = 0; j < 4; ++j) {
    const int c = j * 256 + t;
    const int r = c >> 3;
    const int p = (c & 7) ^ (r & 7);
    gload16(QKV + (row0 + r) * QSTR + colQ + p * 8, (char*)Qs + c * 16);
  }
#pragma unroll
  for (int j = 0; j < 2; ++j) {
    const int c = j * 256 + t;
    const int r = c >> 3;
    const int p = (c & 7) ^ (r & 7);
    gload16(QKV + (kvrow0 + r) * QSTR + colK + p * 8, (char*)Ks[0] + c * 16);
  }
  bf16x8 vv[2];
#pragma unroll
  for (int j = 0; j < 2; ++j) {
    const int c = j * 256 + t;
    const int key = c >> 3, dc = c & 7;
    vv[j] = *(const bf16x8*)(QKV + (kvrow0 + key) * QSTR + colV + dc * 8);
  }
  AVM(0);
#pragma unroll
  for (int j = 0; j < 2; ++j) {
    const int c = j * 256 + t;
    const int key = c >> 3, dc = c & 7;
#pragma unroll
    for (int e = 0; e < 8; ++e) {
      const int d = dc * 8 + e;
      *(__bf16*)((char*)Vt[0] + d * 128 + (((key >> 3) ^ dc) * 16) + (key & 7) * 2) = vv[j][e];
    }
  }
  __syncthreads();

  // hoist Q fragments (B-operand: col=q=l31, k-chunk = kk*16 + h*8)
  bf16x8 bq[4];
  {
    const int qrow = w * 32 + l31;
#pragma unroll
    for (int kk = 0; kk < 4; ++kk) {
      const int p = (kk * 2 + h) ^ (qrow & 7);
      bq[kk] = *(const bf16x8*)((const char*)Qs + qrow * 128 + p * 16);
    }
  }

  f32x16 ctx0, ctx1;
#pragma unroll
  for (int r = 0; r < 16; ++r) { ctx0[r] = 0.f; ctx1[r] = 0.f; }
  float m = -INFINITY, l = 0.f;

  for (int kb = 0; kb < 16; ++kb) {
    const int cur = kb & 1, nxt = cur ^ 1;
    const int kb1 = (kb + 1 < 16) ? kb + 1 : kb;
    const long kr1 = kvrow0 + kb1 * 64;

    // prefetch next tile: V reg-loads first, then K global->LDS
#pragma unroll
    for (int j = 0; j < 2; ++j) {
      const int c = j * 256 + t;
      const int key = c >> 3, dc = c & 7;
      vv[j] = *(const bf16x8*)(QKV + (kr1 + key) * QSTR + colV + dc * 8);
    }
#pragma unroll
    for (int j = 0; j < 2; ++j) {
      const int c = j * 256 + t;
      const int r = c >> 3;
      const int p = (c & 7) ^ (r & 7);
      gload16(QKV + (kr1 + r) * QSTR + colK + p * 8, (char*)Ks[nxt] + c * 16);
    }

    // ---- QK^T swapped: A=K rows(keys), B=Q cols(q) ----
    f32x16 s0, s1;
#pragma unroll
    for (int r = 0; r < 16; ++r) { s0[r] = 0.f; s1[r] = 0.f; }
    __builtin_amdgcn_s_setprio(1);
#pragma unroll
    for (int kk = 0; kk < 4; ++kk) {
      const int pce = kk * 2 + h;
      const int p0i = pce ^ (l31 & 7);
      bf16x8 ak0 = *(const bf16x8*)((const char*)Ks[cur] + l31 * 128 + p0i * 16);
      bf16x8 ak1 = *(const bf16x8*)((const char*)Ks[cur] + (32 + l31) * 128 + p0i * 16);
      s0 = __builtin_amdgcn_mfma_f32_32x32x16_bf16(ak0, bq[kk], s0, 0, 0, 0);
      s1 = __builtin_amdgcn_mfma_f32_32x32x16_bf16(ak1, bq[kk], s1, 0, 0, 0);
    }
    __builtin_amdgcn_s_setprio(0);

    // ---- in-register online softmax (raw units; scale 1/8 folded into exp) ----
    float mx = s0[0];
#pragma unroll
    for (int r = 1; r < 16; ++r) mx = fmaxf(mx, s0[r]);
#pragma unroll
    for (int r = 0; r < 16; ++r) mx = fmaxf(mx, s1[r]);
    mx = fmaxf(mx, __shfl_xor(mx, 32));

    if (!__all(mx - m <= 64.f)) {   // defer-max THR = 8 (x8 raw)
      const float mn = fmaxf(m, mx);
      const float corr = __expf((m - mn) * 0.125f);
      l *= corr;
#pragma unroll
      for (int r = 0; r < 16; ++r) { ctx0[r] *= corr; ctx1[r] *= corr; }
      m = mn;
    }
    f32x16 p0, p1;
    float rs = 0.f;
#pragma unroll
    for (int r = 0; r < 16; ++r) { p0[r] = __expf((s0[r] - m) * 0.125f); rs += p0[r]; }
#pragma unroll
    for (int r = 0; r < 16; ++r) { p1[r] = __expf((s1[r] - m) * 0.125f); rs += p1[r]; }
    rs += __shfl_xor(rs, 32);
    l += rs;

    // ---- write V[t+1] transpose into Vt[nxt] ----
    AVM(2);
#pragma unroll
    for (int j = 0; j < 2; ++j) {
      const int c = j * 256 + t;
      const int key = c >> 3, dc = c & 7;
#pragma unroll
      for (int e = 0; e < 8; ++e) {
        const int d = dc * 8 + e;
        *(__bf16*)((char*)Vt[nxt] + d * 128 + (((key >> 3) ^ dc) * 16) + (key & 7) * 2) = vv[j][e];
      }
    }

    // ---- build PV B-operand frags: pa[ks][e] = P[k=ks*16+h*8+e][q] ----
    bf16x8 paf[4];
#pragma unroll
    for (int ks = 0; ks < 4; ++ks) {
      const int base = (ks & 1) * 8;
      unsigned a0, a1, b0, b1;
      if (ks < 2) {
        CVTPK(a0, p0[base + 0], p0[base + 1]);
        CVTPK(b0, p0[base + 4], p0[base + 5]);
        CVTPK(a1, p0[base + 2], p0[base + 3]);
        CVTPK(b1, p0[base + 6], p0[base + 7]);
      } else {
        CVTPK(a0, p1[base + 0], p1[base + 1]);
        CVTPK(b0, p1[base + 4], p1[base + 5]);
        CVTPK(a1, p1[base + 2], p1[base + 3]);
        CVTPK(b1, p1[base + 6], p1[base + 7]);
      }
      PLSWAP(a0, b0);
      PLSWAP(a1, b1);
      u32x4 wv4; wv4[0] = a0; wv4[1] = a1; wv4[2] = b0; wv4[3] = b1;
      paf[ks] = __builtin_bit_cast(bf16x8, wv4);
    }

    // ---- PV swapped: ctx(O^T) += mfma(A=Vt rows(d), B=P cols(q)) ----
    __builtin_amdgcn_s_setprio(1);
#pragma unroll
    for (int ks = 0; ks < 4; ++ks) {
      const int pce = ks * 2 + h;
      bf16x8 av0 = *(const bf16x8*)((const char*)Vt[cur] + l31 * 128 + ((pce ^ (l31 >> 3)) * 16));
      bf16x8 av1 = *(const bf16x8*)((const char*)Vt[cur] + (32 + l31) * 128 + ((pce ^ (4 + (l31 >> 3))) * 16));
      ctx0 = __builtin_amdgcn_mfma_f32_32x32x16_bf16(av0, paf[ks], ctx0, 0, 0, 0);
      ctx1 = __builtin_amdgcn_mfma_f32_32x32x16_bf16(av1, paf[ks], ctx1, 0, 0, 0);
    }
    __builtin_amdgcn_s_setprio(0);

    __syncthreads();
  }

  // ---- epilogue: O[q][d] = ctx^T / l ----
  const float inv = 1.0f / l;
  const long orow = row0 + w * 32 + l31;
#pragma unroll
  for (int f = 0; f < 2; ++f)
#pragma unroll
    for (int tq = 0; tq < 4; ++tq) {
      bf16x4 o;
#pragma unroll
      for (int e = 0; e < 4; ++e) {
        const float v = (f ? ctx1[tq * 4 + e] : ctx0[tq * 4 + e]) * inv;
        o[e] = (__bf16)v;
      }
      const int col = colQ + f * 32 + tq * 8 + h * 4;
      *(bf16x4*)&Og[orow * E + col] = o;
    }
}

// ---------------------------------------------------------------------------
extern "C" void kernel_launch(void* const* d_in, const int* in_sizes, int n_in,
                              void* d_out, int out_size, void* d_ws, size_t ws_size,
                              hipStream_t stream) {
  const float* x     = (const float*)d_in[0];
  const float* ln1g  = (const float*)d_in[1];
  const float* ln1b  = (const float*)d_in[2];
  const float* ln2g  = (const float*)d_in[3];
  const float* ln2b  = (const float*)d_in[4];
  const float* wq    = (const float*)d_in[5];
  const float* bq    = (const float*)d_in[6];
  const float* wk    = (const float*)d_in[7];
  const float* bk    = (const float*)d_in[8];
  const float* wv    = (const float*)d_in[9];
  const float* bv    = (const float*)d_in[10];
  const float* wo    = (const float*)d_in[11];
  const float* bo    = (const float*)d_in[12];
  const float* w1    = (const float*)d_in[13];
  const float* b1    = (const float*)d_in[14];
  const float* w2    = (const float*)d_in[15];
  const float* b2    = (const float*)d_in[16];
  float* out = (float*)d_out;

  char* ws = (char*)d_ws;
  const size_t MB = 1024 * 1024;
  __bf16* Wqkv = (__bf16*)(ws + 0 * MB);    // [3072][1024] bf16, 6MB
  __bf16* Wot  = (__bf16*)(ws + 6 * MB);    // [1024][1024] 2MB
  __bf16* W1t  = (__bf16*)(ws + 8 * MB);    // [4096][1024] 8MB
  __bf16* W2t  = (__bf16*)(ws + 16 * MB);   // [1024][4096] 8MB
  __bf16* h    = (__bf16*)(ws + 24 * MB);   // [8192][1024] 16MB
  __bf16* qkv  = (__bf16*)(ws + 40 * MB);   // [8192][3072] 48MB
  __bf16* ctx  = (__bf16*)(ws + 88 * MB);   // [8192][1024] 16MB
  __bf16* ff1  = (__bf16*)(ws + 40 * MB);   // [8192][4096] 64MB, aliases qkv
  __bf16* tmp0 = (__bf16*)(ws + 0 * MB);    // FF2 partial 0 (weights dead)
  __bf16* tmp1 = (__bf16*)(ws + 24 * MB);   // FF2 partial 1 (h dead)

  const dim3 blk(256);
  const dim3 blk512(512);
  const size_t GLDS8P  = 131072;                 // 2 bufs x 64KB
  const size_t GLDS128 = 5 * (128 * 64 + 16384); // 120 KB, DEPTH=5

  // all six weights -> bf16 transposed [N][K] in ONE launch
  wconv6_kernel<<<12288, blk, 0, stream>>>(wq, wk, wv, wo, w1, w2,
                                           Wqkv, Wot, W1t, W2t);

  // LN1
  ln_kernel<<<TOK, blk, 0, stream>>>(x, ln1g, ln1b, h);

  // fused QKV projection: [8192][3072]   grid 12x32 = 384 blocks
  gemm8p_kernel<false, false, true, 3><<<dim3(3072 / 256, TOK / 256), blk512, GLDS8P, stream>>>(
      h, Wqkv, bq, bk, bv, nullptr, qkv, nullptr, TOK, 3072, E, E);

  // attention: 8 q-blocks of 128 rows x 128 (b,h)
  attn_kernel<<<dim3(8, 128), blk, 0, stream>>>(qkv, ctx);

  // O projection + residual(x) -> d_out (fp32)   grid 4x64 = 256 blocks
  gemmk_kernel<128, 5, false, true, false, 1><<<dim3(E / 256, TOK / 128), blk512, GLDS128, stream>>>(
      ctx, Wot, bo, nullptr, nullptr, x, out, nullptr, TOK, E, E, E);

  // LN2 on d_out
  ln_kernel<<<TOK, blk, 0, stream>>>(out, ln2g, ln2b, h);

  // FF1 with ReLU -> ff1 (bf16)   grid 16x32 = 512 blocks
  gemm8p_kernel<true, false, true, 1><<<dim3(HID / 256, TOK / 256), blk512, GLDS8P, stream>>>(
      h, W1t, b1, nullptr, nullptr, nullptr, ff1, nullptr, TOK, HID, E, E);

  // FF2 split-K=2: partials -> tmp0/tmp1   grid 4x32x2 = 256 blocks
  gemm8p_kernel<false, false, true, 0><<<dim3(E / 256, TOK / 256, 2), blk512, GLDS8P, stream>>>(
      ff1, W2t, nullptr, nullptr, nullptr, nullptr, tmp0, tmp1, TOK, E, HID / 2, HID);

  // reduce: out = out(resid) + b2 + tmp0 + tmp1
  reduce2_kernel<<<TOK * E / 1024, blk, 0, stream>>>(out, tmp0, tmp1, b2);
}